// Round 1
// 459.954 us; speedup vs baseline: 1.2192x; 1.2192x over previous
//
#include <hip/hip_runtime.h>
#include <hip/hip_bf16.h>
#include <math.h>

// RGA module: B=64, C=128, HW=784, IC=32, IS=196, DS=49, DC=8.
// Rank-32 factorization removes Gs [b,784,784] and Gc [b,128,128] entirely.
// R5: k8 on MFMA. R7: k4 spatial chain fully on MFMA.
// R8: k10 split into s-chunk partials (896 blocks) + reduce.
// R9: k1+k2 fused into one LDS-tiled f32 GEMM (k1k2_tile). Old k1 issued 128
//     scalar 2B loads/thread (VMEM-instruction bound, 64x L2 re-reads, 115us);
//     new kernel stages x tile once in LDS, 6o x 4p register tile per thread,
//     gxs rows 64-95 fused with LDS reduction (k2 deleted). f32 throughout --
//     precision identical to old path for both dtype flags.

#define BB 64
#define CC 128
#define HW 784
#define IC 32
#define IS 196
#define DS 49

// ---- wf (converted f32 inputs) offsets, padded to 4-float alignment ----
#define O_THW 0
#define O_PHW 4096
#define O_GGSW 8192
#define O_GXSW 315520
#define O_WS1W 319616
#define O_WS2W 329272
#define O_THCW 329324
#define O_PHCW 482988
#define O_GGCW 636652
#define O_GXCW 644844
#define O_WC1W 798508
#define O_WC2W 798772
#define O_THS 798780
#define O_THB 798812
#define O_PHS 798844
#define O_PHB 798876
#define O_GGSS 798908
#define O_GGSB 799104
#define O_GXSS 799300
#define O_GXSB 799332
#define O_WS1S 799364
#define O_WS1B 799416
#define O_WS2S 799468
#define O_WS2B 799472
#define O_THCS 799476
#define O_THCB 799672
#define O_PHCS 799868
#define O_PHCB 800064
#define O_GGCS 800260
#define O_GGCB 800292
#define O_GXCS 800324
#define O_GXCB 800520
#define O_WC1S 800716
#define O_WC1B 800724
#define O_WC2S 800732
#define O_WC2B 800736
#define WF_TOTAL 800768

static const int SRC_SIZES[36] = {
  4096,4096,307328,4096,9653,49,153664,153664,8192,153664,264,8,
  32,32,32,32,196,196,32,32,49,49,1,1,196,196,196,196,32,32,196,196,8,8,1,1};
static const int DST_OFF[36] = {
  O_THW,O_PHW,O_GGSW,O_GXSW,O_WS1W,O_WS2W,O_THCW,O_PHCW,O_GGCW,O_GXCW,O_WC1W,O_WC2W,
  O_THS,O_THB,O_PHS,O_PHB,O_GGSS,O_GGSB,O_GXSS,O_GXSB,O_WS1S,O_WS1B,O_WS2S,O_WS2B,
  O_THCS,O_THCB,O_PHCS,O_PHCB,O_GGCS,O_GGCB,O_GXCS,O_GXCB,O_WC1S,O_WC1B,O_WC2S,O_WC2B};

struct ConvArgs { const void* p[36]; int cum[37]; int dst[36]; };

typedef __attribute__((ext_vector_type(8))) short short8;   // 8 bf16 (4 VGPRs)
typedef __attribute__((ext_vector_type(4))) float fragf4;   // MFMA C/D

union FragU { unsigned int w[4]; short8 s8; };

__device__ __forceinline__ float sigf(float v){ return 1.0f/(1.0f+expf(-v)); }
__device__ __forceinline__ float hb2f(unsigned short h){ return __uint_as_float(((unsigned)h)<<16); }
__device__ __forceinline__ unsigned short f2hb(float v){
  __hip_bfloat16 hb = __float2bfloat16(v);
  return *reinterpret_cast<unsigned short*>(&hb);
}
__device__ __forceinline__ float loadx(const void* x, int flag, size_t idx){
  if (flag) return hb2f(((const unsigned short*)x)[idx]);
  return ((const float*)x)[idx];
}

// ---- kd: dtype probe. bf16 data -> ~all sane exponents; f32-misread -> ~62%.
__global__ void kd_detect(const void* x, int* flag){
  __shared__ int cnt[256];
  int t = threadIdx.x;
  const unsigned short* h = (const unsigned short*)x;
  int c = 0;
  for (int k=0;k<4;k++){
    unsigned short v = h[t*4+k];
    int e = (v>>7)&0xFF;
    c += (e==0 || (e>=97 && e<=157)) ? 1 : 0;
  }
  cnt[t] = c;
  __syncthreads();
  for (int s=128; s; s>>=1){ if (t<s) cnt[t]+=cnt[t+s]; __syncthreads(); }
  if (t==0) *flag = (cnt[0] >= 973) ? 1 : 0;
}

// ---- kc: convert all non-x inputs to f32 arena wf
__global__ void kc_convert(ConvArgs a, const int* flagp, float* wf){
  int flag = *flagp;
  int g = blockIdx.x*256 + threadIdx.x;
  if (g >= a.cum[36]) return;
  int i = 0;
  while (g >= a.cum[i+1]) i++;
  int local = g - a.cum[i];
  float v;
  if (flag) v = hb2f(((const unsigned short*)a.p[i])[local]);
  else      v = ((const float*)a.p[i])[local];
  wf[a.dst[i] + local] = v;
}

// ---- kw: bf16 copies of thc/phc/gxc weights for MFMA (lossless if input bf16)
__global__ void kw_wbf(const float* wf, unsigned short* wbf){
  int i = blockIdx.x*256 + threadIdx.x;
  if (i >= 3*IS*HW) return;
  int which = i/(IS*HW), r = i - which*(IS*HW);
  int off = which==0?O_THCW:(which==1?O_PHCW:O_GXCW);
  wbf[i] = f2hb(wf[off + r]);
}

// ---- k0: ws1bf [64][224] bf16 (zero-padded W1aug: col0 = gx weight)
__global__ void k0_ws1bf(const float* wf, unsigned int* ws1bf32){
  int i = blockIdx.x*256 + threadIdx.x;      // 64*112 u32
  if (i >= 64*112) return;
  int o2 = i/112, k2 = i - o2*112;
  int k = k2*2;
  float v0 = (o2<DS && k<197)   ? wf[O_WS1W + o2*197 + k]   : 0.f;
  float v1 = (o2<DS && k+1<197) ? wf[O_WS1W + o2*197 + k+1] : 0.f;
  ws1bf32[i] = (unsigned)f2hb(v0) | ((unsigned)f2hb(v1)<<16);
}

// ---- k1k2 (R9): fused theta/phi/g_xs projections, LDS-tiled f32 GEMM.
// Block = (b, 64-p tile). A rows 0-31: theta (th_w), 32-63: phi (ph_w),
// 64-95: gxs (gxs_w, relu-scaled then mean over rows -> g_xs).
// x tile staged once to LDS [128c][64p]; thread tile 6o x 4p; w rows from
// global (49 KB, L2-resident, broadcast across 16 p-lanes).
#define GPS 68   // Gp dword stride (bank-spread)
__global__ __launch_bounds__(256) void k1k2_tile(const void* x, const int* flagp,
    const float* wf, float* theta, float* phi, float* g_xs)
{
  __shared__ __align__(16) float Xl[128*64];
  __shared__ __align__(16) float Gp[32*GPS];
  int flag = *flagp;
  int t = threadIdx.x;
  int pt = blockIdx.x % 13, b = blockIdx.x / 13;
  int p0 = pt*64;

  // stage x tile [c][p] -> f32 LDS (x read exactly once from global)
  for (int i=t; i<128*16; i+=256){
    int c = i>>4, q = i&15;
    int p = p0 + q*4;
    float4 v = make_float4(0.f,0.f,0.f,0.f);
    if (p < HW){
      if (flag){
        const unsigned short* xs = (const unsigned short*)x
            + (size_t)b*CC*HW + (size_t)c*HW + p;
        uint2 u = *(const uint2*)xs;
        v.x = hb2f((unsigned short)(u.x & 0xffff));
        v.y = hb2f((unsigned short)(u.x >> 16));
        v.z = hb2f((unsigned short)(u.y & 0xffff));
        v.w = hb2f((unsigned short)(u.y >> 16));
      } else {
        v = *(const float4*)((const float*)x + (size_t)b*CC*HW + (size_t)c*HW + p);
      }
    }
    *(float4*)(Xl + c*64 + q*4) = v;
  }

  int tp = t & 15, to = t >> 4;         // 16 p-lanes x 16 o-groups
  const float* wrow[6];
  #pragma unroll
  for (int i=0;i<6;i++){
    int o = to*6 + i;                   // th/ph rows 0-63 are contiguous at wf+0
    wrow[i] = wf + (o < 64 ? o*CC : O_GXSW + (o-64)*CC);
  }
  float4 acc[6];
  #pragma unroll
  for (int i=0;i<6;i++) acc[i] = make_float4(0.f,0.f,0.f,0.f);
  __syncthreads();

  int px = tp*4;
  for (int c=0;c<CC;c+=4){
    float4 x0 = *(const float4*)(Xl + (c+0)*64 + px);
    float4 x1 = *(const float4*)(Xl + (c+1)*64 + px);
    float4 x2 = *(const float4*)(Xl + (c+2)*64 + px);
    float4 x3 = *(const float4*)(Xl + (c+3)*64 + px);
    #pragma unroll
    for (int i=0;i<6;i++){
      float4 wv = *(const float4*)(wrow[i] + c);
      acc[i].x += wv.x*x0.x + wv.y*x1.x + wv.z*x2.x + wv.w*x3.x;
      acc[i].y += wv.x*x0.y + wv.y*x1.y + wv.z*x2.y + wv.w*x3.y;
      acc[i].z += wv.x*x0.z + wv.y*x1.z + wv.z*x2.z + wv.w*x3.z;
      acc[i].w += wv.x*x0.w + wv.y*x1.w + wv.z*x2.w + wv.w*x3.w;
    }
  }

  #pragma unroll
  for (int i=0;i<6;i++){
    int o = to*6 + i;
    float sc, sh;
    if (o < 32)      { sc = wf[O_THS+o];     sh = wf[O_THB+o]; }
    else if (o < 64) { sc = wf[O_PHS+o-32];  sh = wf[O_PHB+o-32]; }
    else             { sc = wf[O_GXSS+o-64]; sh = wf[O_GXSB+o-64]; }
    float4 r;
    r.x = fmaxf(sc*acc[i].x + sh, 0.f);
    r.y = fmaxf(sc*acc[i].y + sh, 0.f);
    r.z = fmaxf(sc*acc[i].z + sh, 0.f);
    r.w = fmaxf(sc*acc[i].w + sh, 0.f);
    if (o < 64){
      float* dst = (o < 32) ? theta + ((size_t)b*IC + o)*HW
                            : phi   + ((size_t)b*IC + o-32)*HW;
      int p = p0 + px;
      if (p < HW) *(float4*)(dst + p) = r;
    } else {
      *(float4*)(Gp + (o-64)*GPS + px) = r;
    }
  }
  __syncthreads();
  if (t < 64){
    float g = 0.f;
    #pragma unroll
    for (int o=0;o<32;o++) g += Gp[o*GPS + t];
    int p = p0 + t;
    if (p < HW) g_xs[(size_t)b*HW + p] = g*(1.f/32.f);
  }
}

// ---- k3 v2: Aphi[b,o,c] = sum_j ggs_w[o,j]*phi[b,c,j] ; Atheta with w2/theta
__global__ __launch_bounds__(64) void k3_afact(const float* wf, const float* theta,
                                               const float* phi,
                                               float* Aphi, float* Atheta){
  __shared__ __align__(16) float Wl[32*60];
  __shared__ __align__(16) float Sl[32*60];
  int t = threadIdx.x;                     // 64 threads
  int ot = blockIdx.x % 7;
  int b  = (blockIdx.x/7) & 63;
  int which = blockIdx.x / (7*64);
  const float* src = which ? theta : phi;
  float* dst = which ? Atheta : Aphi;
  const float* wbase = wf + O_GGSW + (which ? HW : 0);
  int o0 = ot*32;
  int oq = t & 7, cq = t >> 3;
  float acc[4][4];
  #pragma unroll
  for (int oo=0;oo<4;oo++)
    #pragma unroll
    for (int cc=0;cc<4;cc++) acc[oo][cc]=0.f;

  for (int ch=0; ch<14; ch++){
    int j0 = ch*56;
    __syncthreads();
    #pragma unroll
    for (int pass=0; pass<7; pass++){
      int i = pass*64 + t;                 // 448 quads each for W and S
      int row = i/14, jq = i - row*14;
      int o = o0 + row;
      float4 wv = make_float4(0.f,0.f,0.f,0.f);
      if (o < IS) wv = *(const float4*)(wbase + (size_t)o*(2*HW) + j0 + 4*jq);
      *(float4*)(Wl + row*60 + 4*jq) = wv;
      *(float4*)(Sl + row*60 + 4*jq) =
          *(const float4*)(src + ((size_t)b*IC + row)*HW + j0 + 4*jq);
    }
    __syncthreads();
    #pragma unroll
    for (int jq=0; jq<14; jq++){
      float4 w4[4], s4[4];
      #pragma unroll
      for (int oo=0;oo<4;oo++) w4[oo] = *(const float4*)(Wl + (oq+8*oo)*60 + 4*jq);
      #pragma unroll
      for (int cc=0;cc<4;cc++) s4[cc] = *(const float4*)(Sl + (cq+8*cc)*60 + 4*jq);
      #pragma unroll
      for (int oo=0;oo<4;oo++)
        #pragma unroll
        for (int cc=0;cc<4;cc++)
          acc[oo][cc] += w4[oo].x*s4[cc].x + w4[oo].y*s4[cc].y
                       + w4[oo].z*s4[cc].z + w4[oo].w*s4[cc].w;
    }
  }
  #pragma unroll
  for (int oo=0;oo<4;oo++){
    int o = o0 + oq + 8*oo;
    if (o >= IS) continue;
    #pragma unroll
    for (int cc=0;cc<4;cc++){
      int c = cq + 8*cc;
      dst[((size_t)b*IS + o)*IC + c] = acc[oo][cc];
    }
  }
}

// ---- k4 v6 (MFMA): fused spatial chain per (b, 64-p tile).
#define ALS 33    // Al/Sl u32 stride
#define GTS 113   // Gt u32 stride (226 u16)
union K4Sh {
  struct { unsigned int Al[208*ALS]; unsigned int Sl[64*ALS]; } s1;
  unsigned int Gt[64*GTS];
};
__global__ __launch_bounds__(256,3) void k4_mfma(const void* x, const int* flagp,
    const float* wf, const float* theta, const float* phi,
    const float* Aphi, const float* Atheta, const float* g_xs,
    const unsigned int* ws1bf32, unsigned short* x1tp)
{
  __shared__ K4Sh sh;
  __shared__ float ash[64];
  int flag = *flagp;
  int t = threadIdx.x;
  int pt = blockIdx.x % 13, b = blockIdx.x / 13;
  int p0 = pt*64;
  int lane = t & 63, w = t >> 6;
  int col = lane & 15, kq = lane >> 4;

  const float* Ab = Aphi   + (size_t)b*IS*IC;
  const float* Tb = Atheta + (size_t)b*IS*IC;
  for (int i=t; i<208*32; i+=256){
    int o = i>>5, cp = i&31;
    unsigned int v = 0u;
    if (o < IS){
      const float* src = (cp<16 ? Ab : Tb) + o*IC + (cp&15)*2;
      v = (unsigned)f2hb(src[0]) | ((unsigned)f2hb(src[1])<<16);
    }
    sh.s1.Al[o*ALS + cp] = v;
  }
  for (int i=t; i<32*64; i+=256){
    int c2 = i>>6, pp = i&63;
    int p = p0+pp;
    unsigned int v = 0u;
    if (p < HW){
      int c = c2*2;
      const float* s0 = (c<32   ? theta : phi) + ((size_t)b*IC + (c&31))*HW + p;
      const float* s1 = (c+1<32 ? theta : phi) + ((size_t)b*IC + ((c+1)&31))*HW + p;
      v = (unsigned)f2hb(*s0) | ((unsigned)f2hb(*s1)<<16);
    }
    sh.s1.Sl[pp*ALS + c2] = v;
  }
  __syncthreads();

  fragf4 acc1[13];
  #pragma unroll
  for (int nt=0; nt<13; nt++)
    #pragma unroll
    for (int r=0;r<4;r++) acc1[nt][r] = 0.f;
  #pragma unroll
  for (int kk=0; kk<2; kk++){
    FragU af;
    #pragma unroll
    for (int q=0;q<4;q++) af.w[q] = sh.s1.Sl[(w*16+col)*ALS + kk*16 + kq*4 + q];
    #pragma unroll
    for (int nt=0; nt<13; nt++){
      FragU bf;
      #pragma unroll
      for (int q=0;q<4;q++) bf.w[q] = sh.s1.Al[(nt*16+col)*ALS + kk*16 + kq*4 + q];
      acc1[nt] = __builtin_amdgcn_mfma_f32_16x16x32_bf16(af.s8, bf.s8, acc1[nt], 0,0,0);
    }
  }
  __syncthreads();   // Al/Sl dead; Gt aliases them

  unsigned short* Gt16 = (unsigned short*)sh.Gt;
  for (int i=t; i<64*9; i+=256){
    int pp = i/9, q = i - pp*9;
    sh.Gt[pp*GTS + 104 + q] = 0u;
  }
  if (t < 64){
    int p = p0 + t;
    float gx = (p < HW) ? g_xs[b*HW + p] : 0.f;
    Gt16[t*226 + 0] = f2hb(gx);
  }
  #pragma unroll
  for (int nt=0; nt<13; nt++){
    int o = nt*16 + col;
    float sc = wf[O_GGSS + o], shf = wf[O_GGSB + o];
    #pragma unroll
    for (int r=0;r<4;r++){
      int pp = w*16 + kq*4 + r;
      float g = fmaxf(sc*acc1[nt][r] + shf, 0.f);
      Gt16[pp*226 + 1 + o] = f2hb(g);
    }
  }
  __syncthreads();

  fragf4 acc2[4];
  #pragma unroll
  for (int nt=0; nt<4; nt++)
    #pragma unroll
    for (int r=0;r<4;r++) acc2[nt][r] = 0.f;
  #pragma unroll
  for (int kk=0; kk<7; kk++){
    FragU af;
    #pragma unroll
    for (int q=0;q<4;q++) af.w[q] = sh.Gt[(w*16+col)*GTS + kk*16 + kq*4 + q];
    #pragma unroll
    for (int nt=0; nt<4; nt++){
      FragU bf;
      #pragma unroll
      for (int q=0;q<4;q++) bf.w[q] = ws1bf32[(nt*16+col)*112 + kk*16 + kq*4 + q];
      acc2[nt] = __builtin_amdgcn_mfma_f32_16x16x32_bf16(af.s8, bf.s8, acc2[nt], 0,0,0);
    }
  }

  float wys[4] = {0.f,0.f,0.f,0.f};
  #pragma unroll
  for (int nt=0; nt<4; nt++){
    int o2 = nt*16 + col;
    bool vd = (o2 < DS);
    float s1 = vd ? wf[O_WS1S+o2] : 0.f;
    float b1 = vd ? wf[O_WS1B+o2] : 0.f;
    float w2 = vd ? wf[O_WS2W+o2] : 0.f;
    #pragma unroll
    for (int r=0;r<4;r++){
      float z = fmaxf(s1*acc2[nt][r] + b1, 0.f);
      wys[r] += w2*z;
    }
  }
  #pragma unroll
  for (int m=1; m<16; m<<=1){
    #pragma unroll
    for (int r=0;r<4;r++) wys[r] += __shfl_xor(wys[r], m, 16);
  }
  if (col == 0){
    float s2 = wf[O_WS2S], b2 = wf[O_WS2B];
    #pragma unroll
    for (int r=0;r<4;r++){
      int pp = w*16 + kq*4 + r;
      ash[pp] = sigf(s2*wys[r] + b2);
    }
  }
  __syncthreads();

  for (int i=t; i<CC*64; i+=256){
    int c = i>>6, pp = i&63;
    int p = p0 + pp;
    if (p < HW){
      float v = ash[pp]*loadx(x, flag, (size_t)b*CC*HW + (size_t)c*HW + p);
      x1tp[(size_t)b*CC*HW + (size_t)c*HW + p] = f2hb(v);
    }
  }
}

// ---- k8 v2 (MFMA): out[b,s,c] = relu(sc*(sum_p W[s,p]*x1[b,p,c])+sh)
#define KST 40
__global__ __launch_bounds__(256,1) void k8_mfma(const unsigned short* wbf,
    const unsigned short* x1tp, const float* wf,
    float* thcp, float* phcp, float* gxcp)
{
  __shared__ __align__(16) unsigned short Al[208*KST];
  __shared__ __align__(16) unsigned short Bl[128*KST];
  int t = threadIdx.x;
  int b = blockIdx.x & 63;
  int which = blockIdx.x >> 6;
  const unsigned short* wsrc = wbf + (size_t)which*IS*HW;
  const unsigned short* xsrc = x1tp + (size_t)b*CC*HW;
  int lane = t & 63, w = t >> 6;
  int m16 = lane & 15, kq = lane >> 4;
  fragf4 acc[13][2];
  #pragma unroll
  for (int st=0; st<13; st++)
    #pragma unroll
    for (int ct=0; ct<2; ct++)
      #pragma unroll
      for (int r=0; r<4; r++) acc[st][ct][r] = 0.f;

  for (int kk=0; kk<25; kk++){
    int p0 = kk*32;
    __syncthreads();
    for (int i=t; i<208*4; i+=256){
      int row = i>>2, q = i&3;
      uint4 v = make_uint4(0u,0u,0u,0u);
      int p = p0 + q*8;
      if (row < IS && p+8 <= HW)
        v = *(const uint4*)(wsrc + (size_t)row*HW + p);
      *(uint4*)(Al + row*KST + q*8) = v;
    }
    for (int i=t; i<128*4; i+=256){
      int row = i>>2, q = i&3;
      uint4 v = make_uint4(0u,0u,0u,0u);
      int p = p0 + q*8;
      if (p+8 <= HW)
        v = *(const uint4*)(xsrc + (size_t)row*HW + p);
      *(uint4*)(Bl + row*KST + q*8) = v;
    }
    __syncthreads();
    short8 bfr[2];
    #pragma unroll
    for (int ct=0; ct<2; ct++){
      int n = (w*2+ct)*16 + m16;
      bfr[ct] = *(const short8*)(Bl + n*KST + kq*8);
    }
    #pragma unroll
    for (int st=0; st<13; st++){
      short8 af = *(const short8*)(Al + (st*16+m16)*KST + kq*8);
      acc[st][0] = __builtin_amdgcn_mfma_f32_16x16x32_bf16(af, bfr[0], acc[st][0], 0,0,0);
      acc[st][1] = __builtin_amdgcn_mfma_f32_16x16x32_bf16(af, bfr[1], acc[st][1], 0,0,0);
    }
  }
  const float* ss = wf + (which==0?O_THCS:(which==1?O_PHCS:O_GXCS));
  const float* sb = wf + (which==0?O_THCB:(which==1?O_PHCB:O_GXCB));
  float* dst = which==0?thcp:(which==1?phcp:gxcp);
  #pragma unroll
  for (int st=0; st<13; st++){
    #pragma unroll
    for (int r=0; r<4; r++){
      int s = st*16 + kq*4 + r;
      if (s >= IS) continue;
      float sc = ss[s], sh = sb[s];
      #pragma unroll
      for (int ct=0; ct<2; ct++){
        int c = (w*2+ct)*16 + m16;
        dst[((size_t)b*IS + s)*CC + c] = fmaxf(sc*acc[st][ct][r] + sh, 0.f);
      }
    }
  }
}

// ---- k9: Bph[b,s,o] = sum_j ggc_w[o,j]*phc[b,s,j]; Bth with w2/thc
__global__ void k9_bfact(const float* wf, const float* thcp, const float* phcp,
                         float* Bph, float* Bth)
{
  int gid = blockIdx.x*256 + threadIdx.x;    // 2*64*196*32 exact
  int o = gid & 31;
  int rest = gid >> 5;
  int s = rest % IS;
  int rb = rest / IS;           // [0,128)
  int b = rb & 63, which = rb >> 6;
  const float* src = which ? thcp : phcp;
  const float* wr = wf + O_GGCW + o*256 + which*CC;
  const float* sr = src + ((size_t)b*IS + s)*CC;
  float acc = 0.f;
  #pragma unroll 8
  for (int j=0;j<CC;j+=4){
    float4 wv = *(const float4*)(wr+j);
    float4 sv = *(const float4*)(sr+j);
    acc += wv.x*sv.x + wv.y*sv.y + wv.z*sv.z + wv.w*sv.w;
  }
  float* dst = which ? Bth : Bph;
  dst[((size_t)b*IS + s)*IC + o] = acc;
}

// ---- k10a: s-chunk partial accumulation. Grid (b x 14 chunks), thread (d, o-half).
// part[b][sc][32o][128d]; gxp[b][sc][128d] (o-half 0 only).
__global__ __launch_bounds__(256) void k10a_part(const float* thcp, const float* phcp,
    const float* gxcp, const float* Bph, const float* Bth,
    float* part, float* gxp)
{
  int t = threadIdx.x;
  int d = t & 127, oh = t >> 7;
  int sc = blockIdx.x % 14, b = blockIdx.x / 14;
  int s0 = sc*14;
  float acc[16];
  #pragma unroll
  for (int o=0;o<16;o++) acc[o]=0.f;
  float gxa = 0.f;
  for (int i=0;i<14;i++){
    int s = s0 + i;
    size_t base = ((size_t)b*IS + s)*CC + d;
    float tv = thcp[base], pv = phcp[base];
    if (oh == 0) gxa += gxcp[base];
    const float* bp = Bph + ((size_t)b*IS + s)*IC + oh*16;
    const float* bt = Bth + ((size_t)b*IS + s)*IC + oh*16;
    #pragma unroll
    for (int o=0;o<16;o++) acc[o] += bp[o]*tv + bt[o]*pv;
  }
  float* pb = part + (((size_t)b*14 + sc)*IC + oh*16)*CC + d;
  #pragma unroll
  for (int o=0;o<16;o++) pb[(size_t)o*CC] = acc[o];
  if (oh == 0) gxp[((size_t)b*14 + sc)*CC + d] = gxa;
}

// ---- k10b: reduce 14 chunks + wc1/wc2/sigmoid epilogue -> c_att[b,d]
__global__ void k10b_catt(const float* wf, const float* part, const float* gxp,
                          float* c_att)
{
  int idx = blockIdx.x*256 + threadIdx.x;    // 64*128 exact
  int d = idx & 127;
  int b = idx >> 7;
  float acc[IC];
  #pragma unroll
  for (int o=0;o<IC;o++) acc[o]=0.f;
  float gx = 0.f;
  for (int sc=0; sc<14; sc++){
    gx += gxp[((size_t)b*14 + sc)*CC + d];
    const float* pb = part + ((size_t)b*14 + sc)*IC*CC + d;
    #pragma unroll
    for (int o=0;o<IC;o++) acc[o] += pb[(size_t)o*CC];
  }
  gx *= (1.f/196.f);
  #pragma unroll
  for (int o=0;o<IC;o++) acc[o] = fmaxf(wf[O_GGCS+o]*acc[o]+wf[O_GGCB+o], 0.f);
  float acc2 = 0.f;
  #pragma unroll
  for (int o2=0;o2<8;o2++){
    float tt = wf[O_WC1W + o2*33]*gx;
    #pragma unroll
    for (int o=0;o<IC;o++) tt += wf[O_WC1W + o2*33+1+o]*acc[o];
    float z = fmaxf(wf[O_WC1S+o2]*tt + wf[O_WC1B+o2], 0.f);
    acc2 += wf[O_WC2W+o2]*z;
  }
  c_att[idx] = sigf(wf[O_WC2S]*acc2 + wf[O_WC2B]);
}

// ---- k12 v2: out[b,c,p] = c_att[b,c]*x1tp[b,c,p] — pure streaming
__global__ void k12_final(const int* flagp, const unsigned int* x1tp2,
                          const float* c_att, void* out)
{
  int i = blockIdx.x*256 + threadIdx.x;      // over BB*CC*HW/2 uints, exact
  int flag = *flagp;
  unsigned int v = x1tp2[i];
  float a = c_att[i/392];                    // 392 uints per (b,c) row
  float v0 = a*hb2f((unsigned short)(v & 0xffff));
  float v1 = a*hb2f((unsigned short)(v >> 16));
  if (flag){
    ((unsigned int*)out)[i] = (unsigned)f2hb(v0) | ((unsigned)f2hb(v1)<<16);
  } else {
    ((float*)out)[2*i+0] = v0;
    ((float*)out)[2*i+1] = v1;
  }
}

extern "C" void kernel_launch(void* const* d_in, const int* in_sizes, int n_in,
                              void* d_out, int out_size, void* d_ws, size_t ws_size,
                              hipStream_t stream)
{
  const void* x = d_in[0];

  float* W = (float*)d_ws;
  int*   flag  = (int*)W;                    // W[0..63] reserved
  float* wf    = W + 64;                     // 800768
  float* theta = wf + WF_TOTAL;              // 1605632
  float* phi   = theta + 1605632;            // 1605632
  float* g_xs  = phi + 1605632;              // 50176
  float* Aphi  = g_xs + 50176;               // 401408
  float* Atheta= Aphi + 401408;              // 401408
  unsigned short* x1tp = (unsigned short*)(Atheta + 401408); // 6422528 u16 = 3211264 f32 slots
  float* thcp  = Atheta + 401408 + 3211264;  // 1605632
  float* phcp  = thcp + 1605632;             // 1605632
  float* gxcp  = phcp + 1605632;             // 1605632
  float* Bph   = gxcp + 1605632;             // 401408
  float* Bth   = Bph + 401408;               // 401408
  unsigned int* ws1bf32 = (unsigned int*)(Bth + 401408);  // 7168 u32 (slot 9664)
  float* c_att = (float*)(ws1bf32) + 9664;   // 8192
  unsigned short* wbf = (unsigned short*)(c_att + 8192);  // 460992 u16 (~53.2 MiB total)
  // k10 partials reuse dead theta..Atheta region (4,064,256 contiguous floats):
  float* part = theta;                       // 64*14*32*128 = 3,670,016
  float* gxp  = theta + 3670016;             // 64*14*128  = 114,688 (fits: 3,784,704 < 4,064,256)

  ConvArgs ca;
  ca.cum[0] = 0;
  for (int i=0;i<36;i++){
    ca.p[i] = d_in[i+1];
    ca.cum[i+1] = ca.cum[i] + SRC_SIZES[i];
    ca.dst[i] = DST_OFF[i];
  }

  kd_detect<<<1, 256, 0, stream>>>(x, flag);
  kc_convert<<<(800716+255)/256, 256, 0, stream>>>(ca, flag, wf);
  kw_wbf<<<(3*IS*HW+255)/256, 256, 0, stream>>>(wf, wbf);
  k0_ws1bf<<<(64*112+255)/256, 256, 0, stream>>>(wf, ws1bf32);
  k1k2_tile<<<64*13, 256, 0, stream>>>(x, flag, wf, theta, phi, g_xs);
  k3_afact<<<2*64*7, 64, 0, stream>>>(wf, theta, phi, Aphi, Atheta);
  k4_mfma<<<64*13, 256, 0, stream>>>(x, flag, wf, theta, phi, Aphi, Atheta,
      g_xs, ws1bf32, x1tp);
  k8_mfma<<<3*64, 256, 0, stream>>>(wbf, x1tp, wf, thcp, phcp, gxcp);
  k9_bfact<<<(2*BB*IS*IC)/256, 256, 0, stream>>>(wf, thcp, phcp, Bph, Bth);
  k10a_part<<<64*14, 256, 0, stream>>>(thcp, phcp, gxcp, Bph, Bth, part, gxp);
  k10b_catt<<<(BB*CC)/256, 256, 0, stream>>>(wf, part, gxp, c_att);
  k12_final<<<(BB*CC*HW/2)/256, 256, 0, stream>>>(flag, (const unsigned int*)x1tp,
      c_att, d_out);
}

// Round 2
// 423.500 us; speedup vs baseline: 1.3241x; 1.0861x over previous
//
#include <hip/hip_runtime.h>
#include <hip/hip_bf16.h>
#include <math.h>

// RGA module: B=64, C=128, HW=784, IC=32, IS=196, DS=49, DC=8.
// Rank-32 factorization removes Gs [b,784,784] and Gc [b,128,128] entirely.
// R5: k8 on MFMA. R7: k4 spatial chain fully on MFMA.
// R8: k10 split into s-chunk partials (896 blocks) + reduce.
// R9: k1+k2 fused into one LDS-tiled f32 GEMM (k1k2_tile).
// R10: k3 ported to the k8 MFMA template (old k3: 1 wave/block, 9% occupancy,
//      74.7us latency-bound). theta/phi now stored bf16 (thph, in old phi
//      slot) -- bit-identical inputs for k4's QK^T which already converted;
//      ggs_w pre-converted to bf16 (wggs) alongside thc/phc/gxc weights.

#define BB 64
#define CC 128
#define HW 784
#define IC 32
#define IS 196
#define DS 49

// ---- wf (converted f32 inputs) offsets, padded to 4-float alignment ----
#define O_THW 0
#define O_PHW 4096
#define O_GGSW 8192
#define O_GXSW 315520
#define O_WS1W 319616
#define O_WS2W 329272
#define O_THCW 329324
#define O_PHCW 482988
#define O_GGCW 636652
#define O_GXCW 644844
#define O_WC1W 798508
#define O_WC2W 798772
#define O_THS 798780
#define O_THB 798812
#define O_PHS 798844
#define O_PHB 798876
#define O_GGSS 798908
#define O_GGSB 799104
#define O_GXSS 799300
#define O_GXSB 799332
#define O_WS1S 799364
#define O_WS1B 799416
#define O_WS2S 799468
#define O_WS2B 799472
#define O_THCS 799476
#define O_THCB 799672
#define O_PHCS 799868
#define O_PHCB 800064
#define O_GGCS 800260
#define O_GGCB 800292
#define O_GXCS 800324
#define O_GXCB 800520
#define O_WC1S 800716
#define O_WC1B 800724
#define O_WC2S 800732
#define O_WC2B 800736
#define WF_TOTAL 800768

static const int SRC_SIZES[36] = {
  4096,4096,307328,4096,9653,49,153664,153664,8192,153664,264,8,
  32,32,32,32,196,196,32,32,49,49,1,1,196,196,196,196,32,32,196,196,8,8,1,1};
static const int DST_OFF[36] = {
  O_THW,O_PHW,O_GGSW,O_GXSW,O_WS1W,O_WS2W,O_THCW,O_PHCW,O_GGCW,O_GXCW,O_WC1W,O_WC2W,
  O_THS,O_THB,O_PHS,O_PHB,O_GGSS,O_GGSB,O_GXSS,O_GXSB,O_WS1S,O_WS1B,O_WS2S,O_WS2B,
  O_THCS,O_THCB,O_PHCS,O_PHCB,O_GGCS,O_GGCB,O_GXCS,O_GXCB,O_WC1S,O_WC1B,O_WC2S,O_WC2B};

struct ConvArgs { const void* p[36]; int cum[37]; int dst[36]; };

typedef __attribute__((ext_vector_type(8))) short short8;   // 8 bf16 (4 VGPRs)
typedef __attribute__((ext_vector_type(4))) float fragf4;   // MFMA C/D

union FragU { unsigned int w[4]; short8 s8; };

__device__ __forceinline__ float sigf(float v){ return 1.0f/(1.0f+expf(-v)); }
__device__ __forceinline__ float hb2f(unsigned short h){ return __uint_as_float(((unsigned)h)<<16); }
__device__ __forceinline__ unsigned short f2hb(float v){
  __hip_bfloat16 hb = __float2bfloat16(v);
  return *reinterpret_cast<unsigned short*>(&hb);
}
__device__ __forceinline__ float loadx(const void* x, int flag, size_t idx){
  if (flag) return hb2f(((const unsigned short*)x)[idx]);
  return ((const float*)x)[idx];
}

// ---- kd: dtype probe. bf16 data -> ~all sane exponents; f32-misread -> ~62%.
__global__ void kd_detect(const void* x, int* flag){
  __shared__ int cnt[256];
  int t = threadIdx.x;
  const unsigned short* h = (const unsigned short*)x;
  int c = 0;
  for (int k=0;k<4;k++){
    unsigned short v = h[t*4+k];
    int e = (v>>7)&0xFF;
    c += (e==0 || (e>=97 && e<=157)) ? 1 : 0;
  }
  cnt[t] = c;
  __syncthreads();
  for (int s=128; s; s>>=1){ if (t<s) cnt[t]+=cnt[t+s]; __syncthreads(); }
  if (t==0) *flag = (cnt[0] >= 973) ? 1 : 0;
}

// ---- kc: convert all non-x inputs to f32 arena wf
__global__ void kc_convert(ConvArgs a, const int* flagp, float* wf){
  int flag = *flagp;
  int g = blockIdx.x*256 + threadIdx.x;
  if (g >= a.cum[36]) return;
  int i = 0;
  while (g >= a.cum[i+1]) i++;
  int local = g - a.cum[i];
  float v;
  if (flag) v = hb2f(((const unsigned short*)a.p[i])[local]);
  else      v = ((const float*)a.p[i])[local];
  wf[a.dst[i] + local] = v;
}

// ---- kw: bf16 copies of thc/phc/gxc weights + ggs_w halves (for MFMA)
__global__ void kw_wbf(const float* wf, unsigned short* wbf){
  int i = blockIdx.x*256 + threadIdx.x;
  if (i >= 5*IS*HW) return;
  int which = i/(IS*HW), r = i - which*(IS*HW);
  float v;
  if (which < 3){
    int off = which==0?O_THCW:(which==1?O_PHCW:O_GXCW);
    v = wf[off + r];
  } else {
    int row = r/HW, col = r - row*HW;
    v = wf[O_GGSW + row*(2*HW) + (which-3)*HW + col];
  }
  wbf[i] = f2hb(v);
}

// ---- k0: ws1bf [64][224] bf16 (zero-padded W1aug: col0 = gx weight)
__global__ void k0_ws1bf(const float* wf, unsigned int* ws1bf32){
  int i = blockIdx.x*256 + threadIdx.x;      // 64*112 u32
  if (i >= 64*112) return;
  int o2 = i/112, k2 = i - o2*112;
  int k = k2*2;
  float v0 = (o2<DS && k<197)   ? wf[O_WS1W + o2*197 + k]   : 0.f;
  float v1 = (o2<DS && k+1<197) ? wf[O_WS1W + o2*197 + k+1] : 0.f;
  ws1bf32[i] = (unsigned)f2hb(v0) | ((unsigned)f2hb(v1)<<16);
}

// ---- k1k2 (R9/R10): fused theta/phi/g_xs projections, LDS-tiled f32 GEMM.
// Block = (b, 64-p tile). A rows 0-31: theta (th_w), 32-63: phi (ph_w),
// 64-95: gxs (gxs_w, relu-scaled then mean over rows -> g_xs).
// theta/phi written as bf16 thph[b][64][784] (consumers use bf16 anyway).
#define GPS 68   // Gp dword stride (bank-spread)
__global__ __launch_bounds__(256) void k1k2_tile(const void* x, const int* flagp,
    const float* wf, unsigned short* thph, float* g_xs)
{
  __shared__ __align__(16) float Xl[128*64];
  __shared__ __align__(16) float Gp[32*GPS];
  int flag = *flagp;
  int t = threadIdx.x;
  int pt = blockIdx.x % 13, b = blockIdx.x / 13;
  int p0 = pt*64;

  // stage x tile [c][p] -> f32 LDS (x read exactly once from global)
  for (int i=t; i<128*16; i+=256){
    int c = i>>4, q = i&15;
    int p = p0 + q*4;
    float4 v = make_float4(0.f,0.f,0.f,0.f);
    if (p < HW){
      if (flag){
        const unsigned short* xs = (const unsigned short*)x
            + (size_t)b*CC*HW + (size_t)c*HW + p;
        uint2 u = *(const uint2*)xs;
        v.x = hb2f((unsigned short)(u.x & 0xffff));
        v.y = hb2f((unsigned short)(u.x >> 16));
        v.z = hb2f((unsigned short)(u.y & 0xffff));
        v.w = hb2f((unsigned short)(u.y >> 16));
      } else {
        v = *(const float4*)((const float*)x + (size_t)b*CC*HW + (size_t)c*HW + p);
      }
    }
    *(float4*)(Xl + c*64 + q*4) = v;
  }

  int tp = t & 15, to = t >> 4;         // 16 p-lanes x 16 o-groups
  const float* wrow[6];
  #pragma unroll
  for (int i=0;i<6;i++){
    int o = to*6 + i;                   // th/ph rows 0-63 are contiguous at wf+0
    wrow[i] = wf + (o < 64 ? o*CC : O_GXSW + (o-64)*CC);
  }
  float4 acc[6];
  #pragma unroll
  for (int i=0;i<6;i++) acc[i] = make_float4(0.f,0.f,0.f,0.f);
  __syncthreads();

  int px = tp*4;
  for (int c=0;c<CC;c+=4){
    float4 x0 = *(const float4*)(Xl + (c+0)*64 + px);
    float4 x1 = *(const float4*)(Xl + (c+1)*64 + px);
    float4 x2 = *(const float4*)(Xl + (c+2)*64 + px);
    float4 x3 = *(const float4*)(Xl + (c+3)*64 + px);
    #pragma unroll
    for (int i=0;i<6;i++){
      float4 wv = *(const float4*)(wrow[i] + c);
      acc[i].x += wv.x*x0.x + wv.y*x1.x + wv.z*x2.x + wv.w*x3.x;
      acc[i].y += wv.x*x0.y + wv.y*x1.y + wv.z*x2.y + wv.w*x3.y;
      acc[i].z += wv.x*x0.z + wv.y*x1.z + wv.z*x2.z + wv.w*x3.z;
      acc[i].w += wv.x*x0.w + wv.y*x1.w + wv.z*x2.w + wv.w*x3.w;
    }
  }

  #pragma unroll
  for (int i=0;i<6;i++){
    int o = to*6 + i;
    float sc, sh;
    if (o < 32)      { sc = wf[O_THS+o];     sh = wf[O_THB+o]; }
    else if (o < 64) { sc = wf[O_PHS+o-32];  sh = wf[O_PHB+o-32]; }
    else             { sc = wf[O_GXSS+o-64]; sh = wf[O_GXSB+o-64]; }
    float4 r;
    r.x = fmaxf(sc*acc[i].x + sh, 0.f);
    r.y = fmaxf(sc*acc[i].y + sh, 0.f);
    r.z = fmaxf(sc*acc[i].z + sh, 0.f);
    r.w = fmaxf(sc*acc[i].w + sh, 0.f);
    int p = p0 + px;
    if (o < 64){
      if (p < HW){
        unsigned int lo = (unsigned)f2hb(r.x) | ((unsigned)f2hb(r.y)<<16);
        unsigned int hi = (unsigned)f2hb(r.z) | ((unsigned)f2hb(r.w)<<16);
        *(uint2*)(thph + ((size_t)b*64 + o)*HW + p) = make_uint2(lo, hi);
      }
    } else {
      *(float4*)(Gp + (o-64)*GPS + px) = r;
    }
  }
  __syncthreads();
  if (t < 64){
    float g = 0.f;
    #pragma unroll
    for (int o=0;o<32;o++) g += Gp[o*GPS + t];
    int p = p0 + t;
    if (p < HW) g_xs[(size_t)b*HW + p] = g*(1.f/32.f);
  }
}

// ---- k3 v3 (R10, MFMA): Aphi[b,o,c] = sum_j wggs[0][o,j]*phi[b,c,j];
//      Atheta with wggs[1]/theta. Grid: which(2) x b(64) x M-half(2).
#define K3ST 40
__global__ __launch_bounds__(256) void k3_mfma(const unsigned short* wggs,
    const unsigned short* thph, float* Aphi, float* Atheta)
{
  __shared__ __align__(16) unsigned short Al[112*K3ST];
  __shared__ __align__(16) unsigned short Bl[32*K3ST];
  int t = threadIdx.x;
  int mh = blockIdx.x & 1;
  int b  = (blockIdx.x >> 1) & 63;
  int which = blockIdx.x >> 7;
  int m0 = mh*112;
  const unsigned short* wsrc = wggs + (size_t)which*IS*HW;
  const unsigned short* ssrc = thph + ((size_t)b*64 + (which ? 0 : 32))*HW;
  int lane = t & 63, w = t >> 6;
  int m16 = lane & 15, kq = lane >> 4;
  fragf4 acc[2][2];
  #pragma unroll
  for (int i=0;i<2;i++)
    #pragma unroll
    for (int nt=0;nt<2;nt++)
      #pragma unroll
      for (int r=0;r<4;r++) acc[i][nt][r] = 0.f;

  for (int kk=0; kk<25; kk++){
    int p0 = kk*32;
    __syncthreads();
    for (int i=t; i<112*4; i+=256){
      int row = i>>2, q = i&3;
      uint4 v = make_uint4(0u,0u,0u,0u);
      int gr = m0 + row, p = p0 + q*8;
      if (gr < IS && p+8 <= HW)
        v = *(const uint4*)(wsrc + (size_t)gr*HW + p);
      *(uint4*)(Al + row*K3ST + q*8) = v;
    }
    if (t < 128){
      int row = t>>2, q = t&3;
      uint4 v = make_uint4(0u,0u,0u,0u);
      int p = p0 + q*8;
      if (p+8 <= HW)
        v = *(const uint4*)(ssrc + (size_t)row*HW + p);
      *(uint4*)(Bl + row*K3ST + q*8) = v;
    }
    __syncthreads();
    short8 bfr[2];
    #pragma unroll
    for (int nt=0;nt<2;nt++)
      bfr[nt] = *(const short8*)(Bl + (nt*16+m16)*K3ST + kq*8);
    #pragma unroll
    for (int i=0;i<2;i++){
      int mt = w + 4*i;
      if (mt < 7){
        short8 af = *(const short8*)(Al + (mt*16+m16)*K3ST + kq*8);
        acc[i][0] = __builtin_amdgcn_mfma_f32_16x16x32_bf16(af, bfr[0], acc[i][0], 0,0,0);
        acc[i][1] = __builtin_amdgcn_mfma_f32_16x16x32_bf16(af, bfr[1], acc[i][1], 0,0,0);
      }
    }
  }
  float* dst = which ? Atheta : Aphi;
  #pragma unroll
  for (int i=0;i<2;i++){
    int mt = w + 4*i;
    if (mt >= 7) continue;
    #pragma unroll
    for (int r=0;r<4;r++){
      int o = m0 + mt*16 + kq*4 + r;
      if (o >= IS) continue;
      #pragma unroll
      for (int nt=0;nt<2;nt++){
        int c = nt*16 + m16;
        dst[((size_t)b*IS + o)*IC + c] = acc[i][nt][r];
      }
    }
  }
}

// ---- k4 v7 (MFMA): fused spatial chain per (b, 64-p tile).
#define ALS 33    // Al/Sl u32 stride
#define GTS 113   // Gt u32 stride (226 u16)
union K4Sh {
  struct { unsigned int Al[208*ALS]; unsigned int Sl[64*ALS]; } s1;
  unsigned int Gt[64*GTS];
};
__global__ __launch_bounds__(256,3) void k4_mfma(const void* x, const int* flagp,
    const float* wf, const unsigned short* thph,
    const float* Aphi, const float* Atheta, const float* g_xs,
    const unsigned int* ws1bf32, unsigned short* x1tp)
{
  __shared__ K4Sh sh;
  __shared__ float ash[64];
  int flag = *flagp;
  int t = threadIdx.x;
  int pt = blockIdx.x % 13, b = blockIdx.x / 13;
  int p0 = pt*64;
  int lane = t & 63, w = t >> 6;
  int col = lane & 15, kq = lane >> 4;

  const float* Ab = Aphi   + (size_t)b*IS*IC;
  const float* Tb = Atheta + (size_t)b*IS*IC;
  for (int i=t; i<208*32; i+=256){
    int o = i>>5, cp = i&31;
    unsigned int v = 0u;
    if (o < IS){
      const float* src = (cp<16 ? Ab : Tb) + o*IC + (cp&15)*2;
      v = (unsigned)f2hb(src[0]) | ((unsigned)f2hb(src[1])<<16);
    }
    sh.s1.Al[o*ALS + cp] = v;
  }
  const unsigned short* tb = thph + (size_t)b*64*HW;
  for (int i=t; i<32*64; i+=256){
    int c2 = i>>6, pp = i&63;
    int p = p0+pp;
    unsigned int v = 0u;
    if (p < HW){
      int c = c2*2;
      v = (unsigned)tb[(size_t)c*HW + p] | ((unsigned)tb[(size_t)(c+1)*HW + p]<<16);
    }
    sh.s1.Sl[pp*ALS + c2] = v;
  }
  __syncthreads();

  fragf4 acc1[13];
  #pragma unroll
  for (int nt=0; nt<13; nt++)
    #pragma unroll
    for (int r=0;r<4;r++) acc1[nt][r] = 0.f;
  #pragma unroll
  for (int kk=0; kk<2; kk++){
    FragU af;
    #pragma unroll
    for (int q=0;q<4;q++) af.w[q] = sh.s1.Sl[(w*16+col)*ALS + kk*16 + kq*4 + q];
    #pragma unroll
    for (int nt=0; nt<13; nt++){
      FragU bf;
      #pragma unroll
      for (int q=0;q<4;q++) bf.w[q] = sh.s1.Al[(nt*16+col)*ALS + kk*16 + kq*4 + q];
      acc1[nt] = __builtin_amdgcn_mfma_f32_16x16x32_bf16(af.s8, bf.s8, acc1[nt], 0,0,0);
    }
  }
  __syncthreads();   // Al/Sl dead; Gt aliases them

  unsigned short* Gt16 = (unsigned short*)sh.Gt;
  for (int i=t; i<64*9; i+=256){
    int pp = i/9, q = i - pp*9;
    sh.Gt[pp*GTS + 104 + q] = 0u;
  }
  if (t < 64){
    int p = p0 + t;
    float gx = (p < HW) ? g_xs[b*HW + p] : 0.f;
    Gt16[t*226 + 0] = f2hb(gx);
  }
  #pragma unroll
  for (int nt=0; nt<13; nt++){
    int o = nt*16 + col;
    float sc = wf[O_GGSS + o], shf = wf[O_GGSB + o];
    #pragma unroll
    for (int r=0;r<4;r++){
      int pp = w*16 + kq*4 + r;
      float g = fmaxf(sc*acc1[nt][r] + shf, 0.f);
      Gt16[pp*226 + 1 + o] = f2hb(g);
    }
  }
  __syncthreads();

  fragf4 acc2[4];
  #pragma unroll
  for (int nt=0; nt<4; nt++)
    #pragma unroll
    for (int r=0;r<4;r++) acc2[nt][r] = 0.f;
  #pragma unroll
  for (int kk=0; kk<7; kk++){
    FragU af;
    #pragma unroll
    for (int q=0;q<4;q++) af.w[q] = sh.Gt[(w*16+col)*GTS + kk*16 + kq*4 + q];
    #pragma unroll
    for (int nt=0; nt<4; nt++){
      FragU bf;
      #pragma unroll
      for (int q=0;q<4;q++) bf.w[q] = ws1bf32[(nt*16+col)*112 + kk*16 + kq*4 + q];
      acc2[nt] = __builtin_amdgcn_mfma_f32_16x16x32_bf16(af.s8, bf.s8, acc2[nt], 0,0,0);
    }
  }

  float wys[4] = {0.f,0.f,0.f,0.f};
  #pragma unroll
  for (int nt=0; nt<4; nt++){
    int o2 = nt*16 + col;
    bool vd = (o2 < DS);
    float s1 = vd ? wf[O_WS1S+o2] : 0.f;
    float b1 = vd ? wf[O_WS1B+o2] : 0.f;
    float w2 = vd ? wf[O_WS2W+o2] : 0.f;
    #pragma unroll
    for (int r=0;r<4;r++){
      float z = fmaxf(s1*acc2[nt][r] + b1, 0.f);
      wys[r] += w2*z;
    }
  }
  #pragma unroll
  for (int m=1; m<16; m<<=1){
    #pragma unroll
    for (int r=0;r<4;r++) wys[r] += __shfl_xor(wys[r], m, 16);
  }
  if (col == 0){
    float s2 = wf[O_WS2S], b2 = wf[O_WS2B];
    #pragma unroll
    for (int r=0;r<4;r++){
      int pp = w*16 + kq*4 + r;
      ash[pp] = sigf(s2*wys[r] + b2);
    }
  }
  __syncthreads();

  for (int i=t; i<CC*64; i+=256){
    int c = i>>6, pp = i&63;
    int p = p0 + pp;
    if (p < HW){
      float v = ash[pp]*loadx(x, flag, (size_t)b*CC*HW + (size_t)c*HW + p);
      x1tp[(size_t)b*CC*HW + (size_t)c*HW + p] = f2hb(v);
    }
  }
}

// ---- k8 v2 (MFMA): out[b,s,c] = relu(sc*(sum_p W[s,p]*x1[b,p,c])+sh)
#define KST 40
__global__ __launch_bounds__(256,1) void k8_mfma(const unsigned short* wbf,
    const unsigned short* x1tp, const float* wf,
    float* thcp, float* phcp, float* gxcp)
{
  __shared__ __align__(16) unsigned short Al[208*KST];
  __shared__ __align__(16) unsigned short Bl[128*KST];
  int t = threadIdx.x;
  int b = blockIdx.x & 63;
  int which = blockIdx.x >> 6;
  const unsigned short* wsrc = wbf + (size_t)which*IS*HW;
  const unsigned short* xsrc = x1tp + (size_t)b*CC*HW;
  int lane = t & 63, w = t >> 6;
  int m16 = lane & 15, kq = lane >> 4;
  fragf4 acc[13][2];
  #pragma unroll
  for (int st=0; st<13; st++)
    #pragma unroll
    for (int ct=0; ct<2; ct++)
      #pragma unroll
      for (int r=0; r<4; r++) acc[st][ct][r] = 0.f;

  for (int kk=0; kk<25; kk++){
    int p0 = kk*32;
    __syncthreads();
    for (int i=t; i<208*4; i+=256){
      int row = i>>2, q = i&3;
      uint4 v = make_uint4(0u,0u,0u,0u);
      int p = p0 + q*8;
      if (row < IS && p+8 <= HW)
        v = *(const uint4*)(wsrc + (size_t)row*HW + p);
      *(uint4*)(Al + row*KST + q*8) = v;
    }
    for (int i=t; i<128*4; i+=256){
      int row = i>>2, q = i&3;
      uint4 v = make_uint4(0u,0u,0u,0u);
      int p = p0 + q*8;
      if (p+8 <= HW)
        v = *(const uint4*)(xsrc + (size_t)row*HW + p);
      *(uint4*)(Bl + row*KST + q*8) = v;
    }
    __syncthreads();
    short8 bfr[2];
    #pragma unroll
    for (int ct=0; ct<2; ct++){
      int n = (w*2+ct)*16 + m16;
      bfr[ct] = *(const short8*)(Bl + n*KST + kq*8);
    }
    #pragma unroll
    for (int st=0; st<13; st++){
      short8 af = *(const short8*)(Al + (st*16+m16)*KST + kq*8);
      acc[st][0] = __builtin_amdgcn_mfma_f32_16x16x32_bf16(af, bfr[0], acc[st][0], 0,0,0);
      acc[st][1] = __builtin_amdgcn_mfma_f32_16x16x32_bf16(af, bfr[1], acc[st][1], 0,0,0);
    }
  }
  const float* ss = wf + (which==0?O_THCS:(which==1?O_PHCS:O_GXCS));
  const float* sb = wf + (which==0?O_THCB:(which==1?O_PHCB:O_GXCB));
  float* dst = which==0?thcp:(which==1?phcp:gxcp);
  #pragma unroll
  for (int st=0; st<13; st++){
    #pragma unroll
    for (int r=0; r<4; r++){
      int s = st*16 + kq*4 + r;
      if (s >= IS) continue;
      float sc = ss[s], sh = sb[s];
      #pragma unroll
      for (int ct=0; ct<2; ct++){
        int c = (w*2+ct)*16 + m16;
        dst[((size_t)b*IS + s)*CC + c] = fmaxf(sc*acc[st][ct][r] + sh, 0.f);
      }
    }
  }
}

// ---- k9: Bph[b,s,o] = sum_j ggc_w[o,j]*phc[b,s,j]; Bth with w2/thc
__global__ void k9_bfact(const float* wf, const float* thcp, const float* phcp,
                         float* Bph, float* Bth)
{
  int gid = blockIdx.x*256 + threadIdx.x;    // 2*64*196*32 exact
  int o = gid & 31;
  int rest = gid >> 5;
  int s = rest % IS;
  int rb = rest / IS;           // [0,128)
  int b = rb & 63, which = rb >> 6;
  const float* src = which ? thcp : phcp;
  const float* wr = wf + O_GGCW + o*256 + which*CC;
  const float* sr = src + ((size_t)b*IS + s)*CC;
  float acc = 0.f;
  #pragma unroll 8
  for (int j=0;j<CC;j+=4){
    float4 wv = *(const float4*)(wr+j);
    float4 sv = *(const float4*)(sr+j);
    acc += wv.x*sv.x + wv.y*sv.y + wv.z*sv.z + wv.w*sv.w;
  }
  float* dst = which ? Bth : Bph;
  dst[((size_t)b*IS + s)*IC + o] = acc;
}

// ---- k10a: s-chunk partial accumulation. Grid (b x 14 chunks), thread (d, o-half).
// part[b][sc][32o][128d]; gxp[b][sc][128d] (o-half 0 only).
__global__ __launch_bounds__(256) void k10a_part(const float* thcp, const float* phcp,
    const float* gxcp, const float* Bph, const float* Bth,
    float* part, float* gxp)
{
  int t = threadIdx.x;
  int d = t & 127, oh = t >> 7;
  int sc = blockIdx.x % 14, b = blockIdx.x / 14;
  int s0 = sc*14;
  float acc[16];
  #pragma unroll
  for (int o=0;o<16;o++) acc[o]=0.f;
  float gxa = 0.f;
  for (int i=0;i<14;i++){
    int s = s0 + i;
    size_t base = ((size_t)b*IS + s)*CC + d;
    float tv = thcp[base], pv = phcp[base];
    if (oh == 0) gxa += gxcp[base];
    const float* bp = Bph + ((size_t)b*IS + s)*IC + oh*16;
    const float* bt = Bth + ((size_t)b*IS + s)*IC + oh*16;
    #pragma unroll
    for (int o=0;o<16;o++) acc[o] += bp[o]*tv + bt[o]*pv;
  }
  float* pb = part + (((size_t)b*14 + sc)*IC + oh*16)*CC + d;
  #pragma unroll
  for (int o=0;o<16;o++) pb[(size_t)o*CC] = acc[o];
  if (oh == 0) gxp[((size_t)b*14 + sc)*CC + d] = gxa;
}

// ---- k10b: reduce 14 chunks + wc1/wc2/sigmoid epilogue -> c_att[b,d]
__global__ void k10b_catt(const float* wf, const float* part, const float* gxp,
                          float* c_att)
{
  int idx = blockIdx.x*256 + threadIdx.x;    // 64*128 exact
  int d = idx & 127;
  int b = idx >> 7;
  float acc[IC];
  #pragma unroll
  for (int o=0;o<IC;o++) acc[o]=0.f;
  float gx = 0.f;
  for (int sc=0; sc<14; sc++){
    gx += gxp[((size_t)b*14 + sc)*CC + d];
    const float* pb = part + ((size_t)b*14 + sc)*IC*CC + d;
    #pragma unroll
    for (int o=0;o<IC;o++) acc[o] += pb[(size_t)o*CC];
  }
  gx *= (1.f/196.f);
  #pragma unroll
  for (int o=0;o<IC;o++) acc[o] = fmaxf(wf[O_GGCS+o]*acc[o]+wf[O_GGCB+o], 0.f);
  float acc2 = 0.f;
  #pragma unroll
  for (int o2=0;o2<8;o2++){
    float tt = wf[O_WC1W + o2*33]*gx;
    #pragma unroll
    for (int o=0;o<IC;o++) tt += wf[O_WC1W + o2*33+1+o]*acc[o];
    float z = fmaxf(wf[O_WC1S+o2]*tt + wf[O_WC1B+o2], 0.f);
    acc2 += wf[O_WC2W+o2]*z;
  }
  c_att[idx] = sigf(wf[O_WC2S]*acc2 + wf[O_WC2B]);
}

// ---- k12 v2: out[b,c,p] = c_att[b,c]*x1tp[b,c,p] — pure streaming
__global__ void k12_final(const int* flagp, const unsigned int* x1tp2,
                          const float* c_att, void* out)
{
  int i = blockIdx.x*256 + threadIdx.x;      // over BB*CC*HW/2 uints, exact
  int flag = *flagp;
  unsigned int v = x1tp2[i];
  float a = c_att[i/392];                    // 392 uints per (b,c) row
  float v0 = a*hb2f((unsigned short)(v & 0xffff));
  float v1 = a*hb2f((unsigned short)(v >> 16));
  if (flag){
    ((unsigned int*)out)[i] = (unsigned)f2hb(v0) | ((unsigned)f2hb(v1)<<16);
  } else {
    ((float*)out)[2*i+0] = v0;
    ((float*)out)[2*i+1] = v1;
  }
}

extern "C" void kernel_launch(void* const* d_in, const int* in_sizes, int n_in,
                              void* d_out, int out_size, void* d_ws, size_t ws_size,
                              hipStream_t stream)
{
  const void* x = d_in[0];

  float* W = (float*)d_ws;
  int*   flag  = (int*)W;                    // W[0..63] reserved
  float* wf    = W + 64;                     // 800768
  float* theta = wf + WF_TOTAL;              // 1605632 (scratch; part alias)
  unsigned short* thph = (unsigned short*)(theta + 1605632); // 3211264 u16 (old phi slot)
  float* g_xs  = theta + 2*1605632;          // 50176
  float* Aphi  = g_xs + 50176;               // 401408
  float* Atheta= Aphi + 401408;              // 401408
  unsigned short* x1tp = (unsigned short*)(Atheta + 401408); // 6422528 u16 = 3211264 f32 slots
  float* thcp  = Atheta + 401408 + 3211264;  // 1605632
  float* phcp  = thcp + 1605632;             // 1605632
  float* gxcp  = phcp + 1605632;             // 1605632
  float* Bph   = gxcp + 1605632;             // 401408
  float* Bth   = Bph + 401408;               // 401408
  unsigned int* ws1bf32 = (unsigned int*)(Bth + 401408);  // 7168 u32 (slot 9664)
  float* c_att = (float*)(ws1bf32) + 9664;   // 8192
  unsigned short* wbf = (unsigned short*)(c_att + 8192);  // 768320 u16 (~53.8 MiB total)
  unsigned short* wggs = wbf + 3*IS*HW;      // 2*196*784 u16 (tail of wbf)
  // k10 partials reuse dead theta..Atheta region (4,064,256 contiguous floats):
  float* part = theta;                       // 64*14*32*128 = 3,670,016
  float* gxp  = theta + 3670016;             // 64*14*128  = 114,688 (fits: 3,784,704 < 4,064,256)

  ConvArgs ca;
  ca.cum[0] = 0;
  for (int i=0;i<36;i++){
    ca.p[i] = d_in[i+1];
    ca.cum[i+1] = ca.cum[i] + SRC_SIZES[i];
    ca.dst[i] = DST_OFF[i];
  }

  kd_detect<<<1, 256, 0, stream>>>(x, flag);
  kc_convert<<<(800716+255)/256, 256, 0, stream>>>(ca, flag, wf);
  kw_wbf<<<(5*IS*HW+255)/256, 256, 0, stream>>>(wf, wbf);
  k0_ws1bf<<<(64*112+255)/256, 256, 0, stream>>>(wf, ws1bf32);
  k1k2_tile<<<64*13, 256, 0, stream>>>(x, flag, wf, thph, g_xs);
  k3_mfma<<<2*64*2, 256, 0, stream>>>(wggs, thph, Aphi, Atheta);
  k4_mfma<<<64*13, 256, 0, stream>>>(x, flag, wf, thph, Aphi, Atheta,
      g_xs, ws1bf32, x1tp);
  k8_mfma<<<3*64, 256, 0, stream>>>(wbf, x1tp, wf, thcp, phcp, gxcp);
  k9_bfact<<<(2*BB*IS*IC)/256, 256, 0, stream>>>(wf, thcp, phcp, Bph, Bth);
  k10a_part<<<64*14, 256, 0, stream>>>(thcp, phcp, gxcp, Bph, Bth, part, gxp);
  k10b_catt<<<(BB*CC)/256, 256, 0, stream>>>(wf, part, gxp, c_att);
  k12_final<<<(BB*CC*HW/2)/256, 256, 0, stream>>>(flag, (const unsigned int*)x1tp,
      c_att, d_out);
}

// Round 3
// 388.987 us; speedup vs baseline: 1.4416x; 1.0887x over previous
//
#include <hip/hip_runtime.h>
#include <hip/hip_bf16.h>
#include <math.h>

// RGA module: B=64, C=128, HW=784, IC=32, IS=196, DS=49, DC=8.
// Rank-32 factorization removes Gs [b,784,784] and Gc [b,128,128] entirely.
// R5: k8 on MFMA. R7: k4 spatial chain fully on MFMA.
// R8: k10 split into s-chunk partials (896 blocks) + reduce.
// R9: k1+k2 fused into one LDS-tiled f32 GEMM (k1k2_tile).
// R10: k3 ported to the k8 MFMA template; theta/phi stored bf16 (thph).
// R11: k8 re-gridded. Old: 192 blocks (0.75/CU), occ 7.7%, MfmaUtil 4%,
//      69.7us pure latency starvation. New: merge the 3 'which' GEMMs
//      (shared B=x1[b]; wbf rows already contiguous 588x784) and tile M by
//      48 -> 832 blocks (3.25/CU). XCD-swizzled b so each XCD's L2 holds
//      only its 8 x1[b] panels. LDS 27->14KB, acc 13x2->3x2 frags.

#define BB 64
#define CC 128
#define HW 784
#define IC 32
#define IS 196
#define DS 49

// ---- wf (converted f32 inputs) offsets, padded to 4-float alignment ----
#define O_THW 0
#define O_PHW 4096
#define O_GGSW 8192
#define O_GXSW 315520
#define O_WS1W 319616
#define O_WS2W 329272
#define O_THCW 329324
#define O_PHCW 482988
#define O_GGCW 636652
#define O_GXCW 644844
#define O_WC1W 798508
#define O_WC2W 798772
#define O_THS 798780
#define O_THB 798812
#define O_PHS 798844
#define O_PHB 798876
#define O_GGSS 798908
#define O_GGSB 799104
#define O_GXSS 799300
#define O_GXSB 799332
#define O_WS1S 799364
#define O_WS1B 799416
#define O_WS2S 799468
#define O_WS2B 799472
#define O_THCS 799476
#define O_THCB 799672
#define O_PHCS 799868
#define O_PHCB 800064
#define O_GGCS 800260
#define O_GGCB 800292
#define O_GXCS 800324
#define O_GXCB 800520
#define O_WC1S 800716
#define O_WC1B 800724
#define O_WC2S 800732
#define O_WC2B 800736
#define WF_TOTAL 800768

static const int SRC_SIZES[36] = {
  4096,4096,307328,4096,9653,49,153664,153664,8192,153664,264,8,
  32,32,32,32,196,196,32,32,49,49,1,1,196,196,196,196,32,32,196,196,8,8,1,1};
static const int DST_OFF[36] = {
  O_THW,O_PHW,O_GGSW,O_GXSW,O_WS1W,O_WS2W,O_THCW,O_PHCW,O_GGCW,O_GXCW,O_WC1W,O_WC2W,
  O_THS,O_THB,O_PHS,O_PHB,O_GGSS,O_GGSB,O_GXSS,O_GXSB,O_WS1S,O_WS1B,O_WS2S,O_WS2B,
  O_THCS,O_THCB,O_PHCS,O_PHCB,O_GGCS,O_GGCB,O_GXCS,O_GXCB,O_WC1S,O_WC1B,O_WC2S,O_WC2B};

struct ConvArgs { const void* p[36]; int cum[37]; int dst[36]; };

typedef __attribute__((ext_vector_type(8))) short short8;   // 8 bf16 (4 VGPRs)
typedef __attribute__((ext_vector_type(4))) float fragf4;   // MFMA C/D

union FragU { unsigned int w[4]; short8 s8; };

__device__ __forceinline__ float sigf(float v){ return 1.0f/(1.0f+expf(-v)); }
__device__ __forceinline__ float hb2f(unsigned short h){ return __uint_as_float(((unsigned)h)<<16); }
__device__ __forceinline__ unsigned short f2hb(float v){
  __hip_bfloat16 hb = __float2bfloat16(v);
  return *reinterpret_cast<unsigned short*>(&hb);
}
__device__ __forceinline__ float loadx(const void* x, int flag, size_t idx){
  if (flag) return hb2f(((const unsigned short*)x)[idx]);
  return ((const float*)x)[idx];
}

// ---- kd: dtype probe. bf16 data -> ~all sane exponents; f32-misread -> ~62%.
__global__ void kd_detect(const void* x, int* flag){
  __shared__ int cnt[256];
  int t = threadIdx.x;
  const unsigned short* h = (const unsigned short*)x;
  int c = 0;
  for (int k=0;k<4;k++){
    unsigned short v = h[t*4+k];
    int e = (v>>7)&0xFF;
    c += (e==0 || (e>=97 && e<=157)) ? 1 : 0;
  }
  cnt[t] = c;
  __syncthreads();
  for (int s=128; s; s>>=1){ if (t<s) cnt[t]+=cnt[t+s]; __syncthreads(); }
  if (t==0) *flag = (cnt[0] >= 973) ? 1 : 0;
}

// ---- kc: convert all non-x inputs to f32 arena wf
__global__ void kc_convert(ConvArgs a, const int* flagp, float* wf){
  int flag = *flagp;
  int g = blockIdx.x*256 + threadIdx.x;
  if (g >= a.cum[36]) return;
  int i = 0;
  while (g >= a.cum[i+1]) i++;
  int local = g - a.cum[i];
  float v;
  if (flag) v = hb2f(((const unsigned short*)a.p[i])[local]);
  else      v = ((const float*)a.p[i])[local];
  wf[a.dst[i] + local] = v;
}

// ---- kw: bf16 copies of thc/phc/gxc weights + ggs_w halves (for MFMA)
__global__ void kw_wbf(const float* wf, unsigned short* wbf){
  int i = blockIdx.x*256 + threadIdx.x;
  if (i >= 5*IS*HW) return;
  int which = i/(IS*HW), r = i - which*(IS*HW);
  float v;
  if (which < 3){
    int off = which==0?O_THCW:(which==1?O_PHCW:O_GXCW);
    v = wf[off + r];
  } else {
    int row = r/HW, col = r - row*HW;
    v = wf[O_GGSW + row*(2*HW) + (which-3)*HW + col];
  }
  wbf[i] = f2hb(v);
}

// ---- k0: ws1bf [64][224] bf16 (zero-padded W1aug: col0 = gx weight)
__global__ void k0_ws1bf(const float* wf, unsigned int* ws1bf32){
  int i = blockIdx.x*256 + threadIdx.x;      // 64*112 u32
  if (i >= 64*112) return;
  int o2 = i/112, k2 = i - o2*112;
  int k = k2*2;
  float v0 = (o2<DS && k<197)   ? wf[O_WS1W + o2*197 + k]   : 0.f;
  float v1 = (o2<DS && k+1<197) ? wf[O_WS1W + o2*197 + k+1] : 0.f;
  ws1bf32[i] = (unsigned)f2hb(v0) | ((unsigned)f2hb(v1)<<16);
}

// ---- k1k2 (R9/R10): fused theta/phi/g_xs projections, LDS-tiled f32 GEMM.
#define GPS 68   // Gp dword stride (bank-spread)
__global__ __launch_bounds__(256) void k1k2_tile(const void* x, const int* flagp,
    const float* wf, unsigned short* thph, float* g_xs)
{
  __shared__ __align__(16) float Xl[128*64];
  __shared__ __align__(16) float Gp[32*GPS];
  int flag = *flagp;
  int t = threadIdx.x;
  int pt = blockIdx.x % 13, b = blockIdx.x / 13;
  int p0 = pt*64;

  // stage x tile [c][p] -> f32 LDS (x read exactly once from global)
  for (int i=t; i<128*16; i+=256){
    int c = i>>4, q = i&15;
    int p = p0 + q*4;
    float4 v = make_float4(0.f,0.f,0.f,0.f);
    if (p < HW){
      if (flag){
        const unsigned short* xs = (const unsigned short*)x
            + (size_t)b*CC*HW + (size_t)c*HW + p;
        uint2 u = *(const uint2*)xs;
        v.x = hb2f((unsigned short)(u.x & 0xffff));
        v.y = hb2f((unsigned short)(u.x >> 16));
        v.z = hb2f((unsigned short)(u.y & 0xffff));
        v.w = hb2f((unsigned short)(u.y >> 16));
      } else {
        v = *(const float4*)((const float*)x + (size_t)b*CC*HW + (size_t)c*HW + p);
      }
    }
    *(float4*)(Xl + c*64 + q*4) = v;
  }

  int tp = t & 15, to = t >> 4;         // 16 p-lanes x 16 o-groups
  const float* wrow[6];
  #pragma unroll
  for (int i=0;i<6;i++){
    int o = to*6 + i;                   // th/ph rows 0-63 are contiguous at wf+0
    wrow[i] = wf + (o < 64 ? o*CC : O_GXSW + (o-64)*CC);
  }
  float4 acc[6];
  #pragma unroll
  for (int i=0;i<6;i++) acc[i] = make_float4(0.f,0.f,0.f,0.f);
  __syncthreads();

  int px = tp*4;
  for (int c=0;c<CC;c+=4){
    float4 x0 = *(const float4*)(Xl + (c+0)*64 + px);
    float4 x1 = *(const float4*)(Xl + (c+1)*64 + px);
    float4 x2 = *(const float4*)(Xl + (c+2)*64 + px);
    float4 x3 = *(const float4*)(Xl + (c+3)*64 + px);
    #pragma unroll
    for (int i=0;i<6;i++){
      float4 wv = *(const float4*)(wrow[i] + c);
      acc[i].x += wv.x*x0.x + wv.y*x1.x + wv.z*x2.x + wv.w*x3.x;
      acc[i].y += wv.x*x0.y + wv.y*x1.y + wv.z*x2.y + wv.w*x3.y;
      acc[i].z += wv.x*x0.z + wv.y*x1.z + wv.z*x2.z + wv.w*x3.z;
      acc[i].w += wv.x*x0.w + wv.y*x1.w + wv.z*x2.w + wv.w*x3.w;
    }
  }

  #pragma unroll
  for (int i=0;i<6;i++){
    int o = to*6 + i;
    float sc, sh;
    if (o < 32)      { sc = wf[O_THS+o];     sh = wf[O_THB+o]; }
    else if (o < 64) { sc = wf[O_PHS+o-32];  sh = wf[O_PHB+o-32]; }
    else             { sc = wf[O_GXSS+o-64]; sh = wf[O_GXSB+o-64]; }
    float4 r;
    r.x = fmaxf(sc*acc[i].x + sh, 0.f);
    r.y = fmaxf(sc*acc[i].y + sh, 0.f);
    r.z = fmaxf(sc*acc[i].z + sh, 0.f);
    r.w = fmaxf(sc*acc[i].w + sh, 0.f);
    int p = p0 + px;
    if (o < 64){
      if (p < HW){
        unsigned int lo = (unsigned)f2hb(r.x) | ((unsigned)f2hb(r.y)<<16);
        unsigned int hi = (unsigned)f2hb(r.z) | ((unsigned)f2hb(r.w)<<16);
        *(uint2*)(thph + ((size_t)b*64 + o)*HW + p) = make_uint2(lo, hi);
      }
    } else {
      *(float4*)(Gp + (o-64)*GPS + px) = r;
    }
  }
  __syncthreads();
  if (t < 64){
    float g = 0.f;
    #pragma unroll
    for (int o=0;o<32;o++) g += Gp[o*GPS + t];
    int p = p0 + t;
    if (p < HW) g_xs[(size_t)b*HW + p] = g*(1.f/32.f);
  }
}

// ---- k3 v3 (R10, MFMA): Aphi[b,o,c] = sum_j wggs[0][o,j]*phi[b,c,j];
//      Atheta with wggs[1]/theta. Grid: which(2) x b(64) x M-half(2).
#define K3ST 40
__global__ __launch_bounds__(256) void k3_mfma(const unsigned short* wggs,
    const unsigned short* thph, float* Aphi, float* Atheta)
{
  __shared__ __align__(16) unsigned short Al[112*K3ST];
  __shared__ __align__(16) unsigned short Bl[32*K3ST];
  int t = threadIdx.x;
  int mh = blockIdx.x & 1;
  int b  = (blockIdx.x >> 1) & 63;
  int which = blockIdx.x >> 7;
  int m0 = mh*112;
  const unsigned short* wsrc = wggs + (size_t)which*IS*HW;
  const unsigned short* ssrc = thph + ((size_t)b*64 + (which ? 0 : 32))*HW;
  int lane = t & 63, w = t >> 6;
  int m16 = lane & 15, kq = lane >> 4;
  fragf4 acc[2][2];
  #pragma unroll
  for (int i=0;i<2;i++)
    #pragma unroll
    for (int nt=0;nt<2;nt++)
      #pragma unroll
      for (int r=0;r<4;r++) acc[i][nt][r] = 0.f;

  for (int kk=0; kk<25; kk++){
    int p0 = kk*32;
    __syncthreads();
    for (int i=t; i<112*4; i+=256){
      int row = i>>2, q = i&3;
      uint4 v = make_uint4(0u,0u,0u,0u);
      int gr = m0 + row, p = p0 + q*8;
      if (gr < IS && p+8 <= HW)
        v = *(const uint4*)(wsrc + (size_t)gr*HW + p);
      *(uint4*)(Al + row*K3ST + q*8) = v;
    }
    if (t < 128){
      int row = t>>2, q = t&3;
      uint4 v = make_uint4(0u,0u,0u,0u);
      int p = p0 + q*8;
      if (p+8 <= HW)
        v = *(const uint4*)(ssrc + (size_t)row*HW + p);
      *(uint4*)(Bl + row*K3ST + q*8) = v;
    }
    __syncthreads();
    short8 bfr[2];
    #pragma unroll
    for (int nt=0;nt<2;nt++)
      bfr[nt] = *(const short8*)(Bl + (nt*16+m16)*K3ST + kq*8);
    #pragma unroll
    for (int i=0;i<2;i++){
      int mt = w + 4*i;
      if (mt < 7){
        short8 af = *(const short8*)(Al + (mt*16+m16)*K3ST + kq*8);
        acc[i][0] = __builtin_amdgcn_mfma_f32_16x16x32_bf16(af, bfr[0], acc[i][0], 0,0,0);
        acc[i][1] = __builtin_amdgcn_mfma_f32_16x16x32_bf16(af, bfr[1], acc[i][1], 0,0,0);
      }
    }
  }
  float* dst = which ? Atheta : Aphi;
  #pragma unroll
  for (int i=0;i<2;i++){
    int mt = w + 4*i;
    if (mt >= 7) continue;
    #pragma unroll
    for (int r=0;r<4;r++){
      int o = m0 + mt*16 + kq*4 + r;
      if (o >= IS) continue;
      #pragma unroll
      for (int nt=0;nt<2;nt++){
        int c = nt*16 + m16;
        dst[((size_t)b*IS + o)*IC + c] = acc[i][nt][r];
      }
    }
  }
}

// ---- k4 v7 (MFMA): fused spatial chain per (b, 64-p tile).
#define ALS 33    // Al/Sl u32 stride
#define GTS 113   // Gt u32 stride (226 u16)
union K4Sh {
  struct { unsigned int Al[208*ALS]; unsigned int Sl[64*ALS]; } s1;
  unsigned int Gt[64*GTS];
};
__global__ __launch_bounds__(256,3) void k4_mfma(const void* x, const int* flagp,
    const float* wf, const unsigned short* thph,
    const float* Aphi, const float* Atheta, const float* g_xs,
    const unsigned int* ws1bf32, unsigned short* x1tp)
{
  __shared__ K4Sh sh;
  __shared__ float ash[64];
  int flag = *flagp;
  int t = threadIdx.x;
  int pt = blockIdx.x % 13, b = blockIdx.x / 13;
  int p0 = pt*64;
  int lane = t & 63, w = t >> 6;
  int col = lane & 15, kq = lane >> 4;

  const float* Ab = Aphi   + (size_t)b*IS*IC;
  const float* Tb = Atheta + (size_t)b*IS*IC;
  for (int i=t; i<208*32; i+=256){
    int o = i>>5, cp = i&31;
    unsigned int v = 0u;
    if (o < IS){
      const float* src = (cp<16 ? Ab : Tb) + o*IC + (cp&15)*2;
      v = (unsigned)f2hb(src[0]) | ((unsigned)f2hb(src[1])<<16);
    }
    sh.s1.Al[o*ALS + cp] = v;
  }
  const unsigned short* tb = thph + (size_t)b*64*HW;
  for (int i=t; i<32*64; i+=256){
    int c2 = i>>6, pp = i&63;
    int p = p0+pp;
    unsigned int v = 0u;
    if (p < HW){
      int c = c2*2;
      v = (unsigned)tb[(size_t)c*HW + p] | ((unsigned)tb[(size_t)(c+1)*HW + p]<<16);
    }
    sh.s1.Sl[pp*ALS + c2] = v;
  }
  __syncthreads();

  fragf4 acc1[13];
  #pragma unroll
  for (int nt=0; nt<13; nt++)
    #pragma unroll
    for (int r=0;r<4;r++) acc1[nt][r] = 0.f;
  #pragma unroll
  for (int kk=0; kk<2; kk++){
    FragU af;
    #pragma unroll
    for (int q=0;q<4;q++) af.w[q] = sh.s1.Sl[(w*16+col)*ALS + kk*16 + kq*4 + q];
    #pragma unroll
    for (int nt=0; nt<13; nt++){
      FragU bf;
      #pragma unroll
      for (int q=0;q<4;q++) bf.w[q] = sh.s1.Al[(nt*16+col)*ALS + kk*16 + kq*4 + q];
      acc1[nt] = __builtin_amdgcn_mfma_f32_16x16x32_bf16(af.s8, bf.s8, acc1[nt], 0,0,0);
    }
  }
  __syncthreads();   // Al/Sl dead; Gt aliases them

  unsigned short* Gt16 = (unsigned short*)sh.Gt;
  for (int i=t; i<64*9; i+=256){
    int pp = i/9, q = i - pp*9;
    sh.Gt[pp*GTS + 104 + q] = 0u;
  }
  if (t < 64){
    int p = p0 + t;
    float gx = (p < HW) ? g_xs[b*HW + p] : 0.f;
    Gt16[t*226 + 0] = f2hb(gx);
  }
  #pragma unroll
  for (int nt=0; nt<13; nt++){
    int o = nt*16 + col;
    float sc = wf[O_GGSS + o], shf = wf[O_GGSB + o];
    #pragma unroll
    for (int r=0;r<4;r++){
      int pp = w*16 + kq*4 + r;
      float g = fmaxf(sc*acc1[nt][r] + shf, 0.f);
      Gt16[pp*226 + 1 + o] = f2hb(g);
    }
  }
  __syncthreads();

  fragf4 acc2[4];
  #pragma unroll
  for (int nt=0; nt<4; nt++)
    #pragma unroll
    for (int r=0;r<4;r++) acc2[nt][r] = 0.f;
  #pragma unroll
  for (int kk=0; kk<7; kk++){
    FragU af;
    #pragma unroll
    for (int q=0;q<4;q++) af.w[q] = sh.Gt[(w*16+col)*GTS + kk*16 + kq*4 + q];
    #pragma unroll
    for (int nt=0; nt<4; nt++){
      FragU bf;
      #pragma unroll
      for (int q=0;q<4;q++) bf.w[q] = ws1bf32[(nt*16+col)*112 + kk*16 + kq*4 + q];
      acc2[nt] = __builtin_amdgcn_mfma_f32_16x16x32_bf16(af.s8, bf.s8, acc2[nt], 0,0,0);
    }
  }

  float wys[4] = {0.f,0.f,0.f,0.f};
  #pragma unroll
  for (int nt=0; nt<4; nt++){
    int o2 = nt*16 + col;
    bool vd = (o2 < DS);
    float s1 = vd ? wf[O_WS1S+o2] : 0.f;
    float b1 = vd ? wf[O_WS1B+o2] : 0.f;
    float w2 = vd ? wf[O_WS2W+o2] : 0.f;
    #pragma unroll
    for (int r=0;r<4;r++){
      float z = fmaxf(s1*acc2[nt][r] + b1, 0.f);
      wys[r] += w2*z;
    }
  }
  #pragma unroll
  for (int m=1; m<16; m<<=1){
    #pragma unroll
    for (int r=0;r<4;r++) wys[r] += __shfl_xor(wys[r], m, 16);
  }
  if (col == 0){
    float s2 = wf[O_WS2S], b2 = wf[O_WS2B];
    #pragma unroll
    for (int r=0;r<4;r++){
      int pp = w*16 + kq*4 + r;
      ash[pp] = sigf(s2*wys[r] + b2);
    }
  }
  __syncthreads();

  for (int i=t; i<CC*64; i+=256){
    int c = i>>6, pp = i&63;
    int p = p0 + pp;
    if (p < HW){
      float v = ash[pp]*loadx(x, flag, (size_t)b*CC*HW + (size_t)c*HW + p);
      x1tp[(size_t)b*CC*HW + (size_t)c*HW + p] = f2hb(v);
    }
  }
}

// ---- k8 v3 (R11, MFMA): out[g,c] = relu(sc*(sum_p Wall[g,p]*x1[b,p,c])+sh)
// for g in [0,588) over merged {thc,phc,gxc} weights. Grid: 13 M-tiles x 64 b.
// b XCD-swizzled: consecutive blockIdx (round-robin XCDs) -> disjoint b sets,
// so each XCD's L2 holds only 8 x1[b] panels (1.6 MB).
#define KST 40
__global__ __launch_bounds__(256) void k8_mfma(const unsigned short* wbf,
    const unsigned short* x1tp, const float* wf, float* outp)
{
  __shared__ __align__(16) unsigned short Al[48*KST];
  __shared__ __align__(16) unsigned short Bl[128*KST];
  int t = threadIdx.x;
  int j = blockIdx.x & 63;
  int b = (j&7)*8 + (j>>3);
  int mt = blockIdx.x >> 6;          // 0..12
  int m0 = mt*48;
  const unsigned short* xsrc = x1tp + (size_t)b*CC*HW;
  int lane = t & 63, w = t >> 6;
  int m16 = lane & 15, kq = lane >> 4;
  fragf4 acc[3][2];
  #pragma unroll
  for (int st=0; st<3; st++)
    #pragma unroll
    for (int ct=0; ct<2; ct++)
      #pragma unroll
      for (int r=0; r<4; r++) acc[st][ct][r] = 0.f;

  for (int kk=0; kk<25; kk++){
    int p0 = kk*32;
    __syncthreads();
    if (t < 192){
      int row = t>>2, q = t&3;
      uint4 v = make_uint4(0u,0u,0u,0u);
      int g = m0 + row, p = p0 + q*8;
      if (g < 3*IS && p+8 <= HW)
        v = *(const uint4*)(wbf + (size_t)g*HW + p);
      *(uint4*)(Al + row*KST + q*8) = v;
    }
    for (int i=t; i<128*4; i+=256){
      int row = i>>2, q = i&3;
      uint4 v = make_uint4(0u,0u,0u,0u);
      int p = p0 + q*8;
      if (p+8 <= HW)
        v = *(const uint4*)(xsrc + (size_t)row*HW + p);
      *(uint4*)(Bl + row*KST + q*8) = v;
    }
    __syncthreads();
    short8 bfr[2];
    #pragma unroll
    for (int ct=0; ct<2; ct++){
      int n = (w*2+ct)*16 + m16;
      bfr[ct] = *(const short8*)(Bl + n*KST + kq*8);
    }
    #pragma unroll
    for (int st=0; st<3; st++){
      short8 af = *(const short8*)(Al + (st*16+m16)*KST + kq*8);
      acc[st][0] = __builtin_amdgcn_mfma_f32_16x16x32_bf16(af, bfr[0], acc[st][0], 0,0,0);
      acc[st][1] = __builtin_amdgcn_mfma_f32_16x16x32_bf16(af, bfr[1], acc[st][1], 0,0,0);
    }
  }
  #pragma unroll
  for (int st=0; st<3; st++){
    #pragma unroll
    for (int r=0; r<4; r++){
      int g = m0 + st*16 + kq*4 + r;
      if (g >= 3*IS) continue;
      int which = (g >= 2*IS) ? 2 : (g >= IS ? 1 : 0);
      int s = g - which*IS;
      int so = (which==2) ? O_GXCS : O_THCS + which*392;
      float sc = wf[so + s], sh = wf[so + 196 + s];
      float* dst = outp + (size_t)which*(64*IS*CC) + ((size_t)b*IS + s)*CC;
      #pragma unroll
      for (int ct=0; ct<2; ct++){
        int c = (w*2+ct)*16 + m16;
        dst[c] = fmaxf(sc*acc[st][ct][r] + sh, 0.f);
      }
    }
  }
}

// ---- k9: Bph[b,s,o] = sum_j ggc_w[o,j]*phc[b,s,j]; Bth with w2/thc
__global__ void k9_bfact(const float* wf, const float* thcp, const float* phcp,
                         float* Bph, float* Bth)
{
  int gid = blockIdx.x*256 + threadIdx.x;    // 2*64*196*32 exact
  int o = gid & 31;
  int rest = gid >> 5;
  int s = rest % IS;
  int rb = rest / IS;           // [0,128)
  int b = rb & 63, which = rb >> 6;
  const float* src = which ? thcp : phcp;
  const float* wr = wf + O_GGCW + o*256 + which*CC;
  const float* sr = src + ((size_t)b*IS + s)*CC;
  float acc = 0.f;
  #pragma unroll 8
  for (int j=0;j<CC;j+=4){
    float4 wv = *(const float4*)(wr+j);
    float4 sv = *(const float4*)(sr+j);
    acc += wv.x*sv.x + wv.y*sv.y + wv.z*sv.z + wv.w*sv.w;
  }
  float* dst = which ? Bth : Bph;
  dst[((size_t)b*IS + s)*IC + o] = acc;
}

// ---- k10a: s-chunk partial accumulation. Grid (b x 14 chunks), thread (d, o-half).
// part[b][sc][32o][128d]; gxp[b][sc][128d] (o-half 0 only).
__global__ __launch_bounds__(256) void k10a_part(const float* thcp, const float* phcp,
    const float* gxcp, const float* Bph, const float* Bth,
    float* part, float* gxp)
{
  int t = threadIdx.x;
  int d = t & 127, oh = t >> 7;
  int sc = blockIdx.x % 14, b = blockIdx.x / 14;
  int s0 = sc*14;
  float acc[16];
  #pragma unroll
  for (int o=0;o<16;o++) acc[o]=0.f;
  float gxa = 0.f;
  for (int i=0;i<14;i++){
    int s = s0 + i;
    size_t base = ((size_t)b*IS + s)*CC + d;
    float tv = thcp[base], pv = phcp[base];
    if (oh == 0) gxa += gxcp[base];
    const float* bp = Bph + ((size_t)b*IS + s)*IC + oh*16;
    const float* bt = Bth + ((size_t)b*IS + s)*IC + oh*16;
    #pragma unroll
    for (int o=0;o<16;o++) acc[o] += bp[o]*tv + bt[o]*pv;
  }
  float* pb = part + (((size_t)b*14 + sc)*IC + oh*16)*CC + d;
  #pragma unroll
  for (int o=0;o<16;o++) pb[(size_t)o*CC] = acc[o];
  if (oh == 0) gxp[((size_t)b*14 + sc)*CC + d] = gxa;
}

// ---- k10b: reduce 14 chunks + wc1/wc2/sigmoid epilogue -> c_att[b,d]
__global__ void k10b_catt(const float* wf, const float* part, const float* gxp,
                          float* c_att)
{
  int idx = blockIdx.x*256 + threadIdx.x;    // 64*128 exact
  int d = idx & 127;
  int b = idx >> 7;
  float acc[IC];
  #pragma unroll
  for (int o=0;o<IC;o++) acc[o]=0.f;
  float gx = 0.f;
  for (int sc=0; sc<14; sc++){
    gx += gxp[((size_t)b*14 + sc)*CC + d];
    const float* pb = part + ((size_t)b*14 + sc)*IC*CC + d;
    #pragma unroll
    for (int o=0;o<IC;o++) acc[o] += pb[(size_t)o*CC];
  }
  gx *= (1.f/196.f);
  #pragma unroll
  for (int o=0;o<IC;o++) acc[o] = fmaxf(wf[O_GGCS+o]*acc[o]+wf[O_GGCB+o], 0.f);
  float acc2 = 0.f;
  #pragma unroll
  for (int o2=0;o2<8;o2++){
    float tt = wf[O_WC1W + o2*33]*gx;
    #pragma unroll
    for (int o=0;o<IC;o++) tt += wf[O_WC1W + o2*33+1+o]*acc[o];
    float z = fmaxf(wf[O_WC1S+o2]*tt + wf[O_WC1B+o2], 0.f);
    acc2 += wf[O_WC2W+o2]*z;
  }
  c_att[idx] = sigf(wf[O_WC2S]*acc2 + wf[O_WC2B]);
}

// ---- k12 v2: out[b,c,p] = c_att[b,c]*x1tp[b,c,p] — pure streaming
__global__ void k12_final(const int* flagp, const unsigned int* x1tp2,
                          const float* c_att, void* out)
{
  int i = blockIdx.x*256 + threadIdx.x;      // over BB*CC*HW/2 uints, exact
  int flag = *flagp;
  unsigned int v = x1tp2[i];
  float a = c_att[i/392];                    // 392 uints per (b,c) row
  float v0 = a*hb2f((unsigned short)(v & 0xffff));
  float v1 = a*hb2f((unsigned short)(v >> 16));
  if (flag){
    ((unsigned int*)out)[i] = (unsigned)f2hb(v0) | ((unsigned)f2hb(v1)<<16);
  } else {
    ((float*)out)[2*i+0] = v0;
    ((float*)out)[2*i+1] = v1;
  }
}

extern "C" void kernel_launch(void* const* d_in, const int* in_sizes, int n_in,
                              void* d_out, int out_size, void* d_ws, size_t ws_size,
                              hipStream_t stream)
{
  const void* x = d_in[0];

  float* W = (float*)d_ws;
  int*   flag  = (int*)W;                    // W[0..63] reserved
  float* wf    = W + 64;                     // 800768
  float* theta = wf + WF_TOTAL;              // 1605632 (scratch; part alias)
  unsigned short* thph = (unsigned short*)(theta + 1605632); // 3211264 u16 (old phi slot)
  float* g_xs  = theta + 2*1605632;          // 50176
  float* Aphi  = g_xs + 50176;               // 401408
  float* Atheta= Aphi + 401408;              // 401408
  unsigned short* x1tp = (unsigned short*)(Atheta + 401408); // 6422528 u16 = 3211264 f32 slots
  float* thcp  = Atheta + 401408 + 3211264;  // 1605632
  float* phcp  = thcp + 1605632;             // 1605632
  float* gxcp  = phcp + 1605632;             // 1605632 (thcp/phcp/gxcp contiguous!)
  float* Bph   = gxcp + 1605632;             // 401408
  float* Bth   = Bph + 401408;               // 401408
  unsigned int* ws1bf32 = (unsigned int*)(Bth + 401408);  // 7168 u32 (slot 9664)
  float* c_att = (float*)(ws1bf32) + 9664;   // 8192
  unsigned short* wbf = (unsigned short*)(c_att + 8192);  // 768320 u16 (~53.8 MiB total)
  unsigned short* wggs = wbf + 3*IS*HW;      // 2*196*784 u16 (tail of wbf)
  // k10 partials reuse dead theta..Atheta region (4,064,256 contiguous floats):
  float* part = theta;                       // 64*14*32*128 = 3,670,016
  float* gxp  = theta + 3670016;             // 64*14*128  = 114,688 (fits: 3,784,704 < 4,064,256)

  ConvArgs ca;
  ca.cum[0] = 0;
  for (int i=0;i<36;i++){
    ca.p[i] = d_in[i+1];
    ca.cum[i+1] = ca.cum[i] + SRC_SIZES[i];
    ca.dst[i] = DST_OFF[i];
  }

  kd_detect<<<1, 256, 0, stream>>>(x, flag);
  kc_convert<<<(800716+255)/256, 256, 0, stream>>>(ca, flag, wf);
  kw_wbf<<<(5*IS*HW+255)/256, 256, 0, stream>>>(wf, wbf);
  k0_ws1bf<<<(64*112+255)/256, 256, 0, stream>>>(wf, ws1bf32);
  k1k2_tile<<<64*13, 256, 0, stream>>>(x, flag, wf, thph, g_xs);
  k3_mfma<<<2*64*2, 256, 0, stream>>>(wggs, thph, Aphi, Atheta);
  k4_mfma<<<64*13, 256, 0, stream>>>(x, flag, wf, thph, Aphi, Atheta,
      g_xs, ws1bf32, x1tp);
  k8_mfma<<<13*64, 256, 0, stream>>>(wbf, x1tp, wf, thcp);
  k9_bfact<<<(2*BB*IS*IC)/256, 256, 0, stream>>>(wf, thcp, phcp, Bph, Bth);
  k10a_part<<<64*14, 256, 0, stream>>>(thcp, phcp, gxcp, Bph, Bth, part, gxp);
  k10b_catt<<<(BB*CC)/256, 256, 0, stream>>>(wf, part, gxp, c_att);
  k12_final<<<(BB*CC*HW/2)/256, 256, 0, stream>>>(flag, (const unsigned int*)x1tp,
      c_att, d_out);
}

// Round 4
// 364.988 us; speedup vs baseline: 1.5364x; 1.0658x over previous
//
#include <hip/hip_runtime.h>
#include <hip/hip_bf16.h>
#include <math.h>

// RGA module: B=64, C=128, HW=784, IC=32, IS=196, DS=49, DC=8.
// Rank-32 factorization removes Gs [b,784,784] and Gc [b,128,128] entirely.
// R5: k8 on MFMA. R7: k4 spatial chain fully on MFMA.
// R8: k10 split into s-chunk partials (896 blocks) + reduce.
// R9: k1+k2 fused into one LDS-tiled f32 GEMM (k1k2_tile).
// R10: k3 ported to the k8 MFMA template; theta/phi stored bf16 (thph).
// R11: k8 re-gridded (3 'which' GEMMs merged, 832 blocks, XCD-swizzled b).
// R12: k9 rebuilt. Old: lane-o weight rows 1KB apart -> each float4 load hit
//      32 L1 lines (13M serialized transactions, 60.5us at 2% HBM / 8% VALU).
//      New: weights transposed+float4-chunked in LDS (conflict-free b128,
//      1 instr replaces 32 line-fetches), src rows broadcast-loaded (L1),
//      ~6 rows/thread reuse each weight read. Same f32 accumulation order
//      -> bit-identical results. Grid 512 blocks.

#define BB 64
#define CC 128
#define HW 784
#define IC 32
#define IS 196
#define DS 49

// ---- wf (converted f32 inputs) offsets, padded to 4-float alignment ----
#define O_THW 0
#define O_PHW 4096
#define O_GGSW 8192
#define O_GXSW 315520
#define O_WS1W 319616
#define O_WS2W 329272
#define O_THCW 329324
#define O_PHCW 482988
#define O_GGCW 636652
#define O_GXCW 644844
#define O_WC1W 798508
#define O_WC2W 798772
#define O_THS 798780
#define O_THB 798812
#define O_PHS 798844
#define O_PHB 798876
#define O_GGSS 798908
#define O_GGSB 799104
#define O_GXSS 799300
#define O_GXSB 799332
#define O_WS1S 799364
#define O_WS1B 799416
#define O_WS2S 799468
#define O_WS2B 799472
#define O_THCS 799476
#define O_THCB 799672
#define O_PHCS 799868
#define O_PHCB 800064
#define O_GGCS 800260
#define O_GGCB 800292
#define O_GXCS 800324
#define O_GXCB 800520
#define O_WC1S 800716
#define O_WC1B 800724
#define O_WC2S 800732
#define O_WC2B 800736
#define WF_TOTAL 800768

static const int SRC_SIZES[36] = {
  4096,4096,307328,4096,9653,49,153664,153664,8192,153664,264,8,
  32,32,32,32,196,196,32,32,49,49,1,1,196,196,196,196,32,32,196,196,8,8,1,1};
static const int DST_OFF[36] = {
  O_THW,O_PHW,O_GGSW,O_GXSW,O_WS1W,O_WS2W,O_THCW,O_PHCW,O_GGCW,O_GXCW,O_WC1W,O_WC2W,
  O_THS,O_THB,O_PHS,O_PHB,O_GGSS,O_GGSB,O_GXSS,O_GXSB,O_WS1S,O_WS1B,O_WS2S,O_WS2B,
  O_THCS,O_THCB,O_PHCS,O_PHCB,O_GGCS,O_GGCB,O_GXCS,O_GXCB,O_WC1S,O_WC1B,O_WC2S,O_WC2B};

struct ConvArgs { const void* p[36]; int cum[37]; int dst[36]; };

typedef __attribute__((ext_vector_type(8))) short short8;   // 8 bf16 (4 VGPRs)
typedef __attribute__((ext_vector_type(4))) float fragf4;   // MFMA C/D

union FragU { unsigned int w[4]; short8 s8; };

__device__ __forceinline__ float sigf(float v){ return 1.0f/(1.0f+expf(-v)); }
__device__ __forceinline__ float hb2f(unsigned short h){ return __uint_as_float(((unsigned)h)<<16); }
__device__ __forceinline__ unsigned short f2hb(float v){
  __hip_bfloat16 hb = __float2bfloat16(v);
  return *reinterpret_cast<unsigned short*>(&hb);
}
__device__ __forceinline__ float loadx(const void* x, int flag, size_t idx){
  if (flag) return hb2f(((const unsigned short*)x)[idx]);
  return ((const float*)x)[idx];
}

// ---- kd: dtype probe. bf16 data -> ~all sane exponents; f32-misread -> ~62%.
__global__ void kd_detect(const void* x, int* flag){
  __shared__ int cnt[256];
  int t = threadIdx.x;
  const unsigned short* h = (const unsigned short*)x;
  int c = 0;
  for (int k=0;k<4;k++){
    unsigned short v = h[t*4+k];
    int e = (v>>7)&0xFF;
    c += (e==0 || (e>=97 && e<=157)) ? 1 : 0;
  }
  cnt[t] = c;
  __syncthreads();
  for (int s=128; s; s>>=1){ if (t<s) cnt[t]+=cnt[t+s]; __syncthreads(); }
  if (t==0) *flag = (cnt[0] >= 973) ? 1 : 0;
}

// ---- kc: convert all non-x inputs to f32 arena wf
__global__ void kc_convert(ConvArgs a, const int* flagp, float* wf){
  int flag = *flagp;
  int g = blockIdx.x*256 + threadIdx.x;
  if (g >= a.cum[36]) return;
  int i = 0;
  while (g >= a.cum[i+1]) i++;
  int local = g - a.cum[i];
  float v;
  if (flag) v = hb2f(((const unsigned short*)a.p[i])[local]);
  else      v = ((const float*)a.p[i])[local];
  wf[a.dst[i] + local] = v;
}

// ---- kw: bf16 copies of thc/phc/gxc weights + ggs_w halves (for MFMA)
__global__ void kw_wbf(const float* wf, unsigned short* wbf){
  int i = blockIdx.x*256 + threadIdx.x;
  if (i >= 5*IS*HW) return;
  int which = i/(IS*HW), r = i - which*(IS*HW);
  float v;
  if (which < 3){
    int off = which==0?O_THCW:(which==1?O_PHCW:O_GXCW);
    v = wf[off + r];
  } else {
    int row = r/HW, col = r - row*HW;
    v = wf[O_GGSW + row*(2*HW) + (which-3)*HW + col];
  }
  wbf[i] = f2hb(v);
}

// ---- k0: ws1bf [64][224] bf16 (zero-padded W1aug: col0 = gx weight)
__global__ void k0_ws1bf(const float* wf, unsigned int* ws1bf32){
  int i = blockIdx.x*256 + threadIdx.x;      // 64*112 u32
  if (i >= 64*112) return;
  int o2 = i/112, k2 = i - o2*112;
  int k = k2*2;
  float v0 = (o2<DS && k<197)   ? wf[O_WS1W + o2*197 + k]   : 0.f;
  float v1 = (o2<DS && k+1<197) ? wf[O_WS1W + o2*197 + k+1] : 0.f;
  ws1bf32[i] = (unsigned)f2hb(v0) | ((unsigned)f2hb(v1)<<16);
}

// ---- k1k2 (R9/R10): fused theta/phi/g_xs projections, LDS-tiled f32 GEMM.
#define GPS 68   // Gp dword stride (bank-spread)
__global__ __launch_bounds__(256) void k1k2_tile(const void* x, const int* flagp,
    const float* wf, unsigned short* thph, float* g_xs)
{
  __shared__ __align__(16) float Xl[128*64];
  __shared__ __align__(16) float Gp[32*GPS];
  int flag = *flagp;
  int t = threadIdx.x;
  int pt = blockIdx.x % 13, b = blockIdx.x / 13;
  int p0 = pt*64;

  // stage x tile [c][p] -> f32 LDS (x read exactly once from global)
  for (int i=t; i<128*16; i+=256){
    int c = i>>4, q = i&15;
    int p = p0 + q*4;
    float4 v = make_float4(0.f,0.f,0.f,0.f);
    if (p < HW){
      if (flag){
        const unsigned short* xs = (const unsigned short*)x
            + (size_t)b*CC*HW + (size_t)c*HW + p;
        uint2 u = *(const uint2*)xs;
        v.x = hb2f((unsigned short)(u.x & 0xffff));
        v.y = hb2f((unsigned short)(u.x >> 16));
        v.z = hb2f((unsigned short)(u.y & 0xffff));
        v.w = hb2f((unsigned short)(u.y >> 16));
      } else {
        v = *(const float4*)((const float*)x + (size_t)b*CC*HW + (size_t)c*HW + p);
      }
    }
    *(float4*)(Xl + c*64 + q*4) = v;
  }

  int tp = t & 15, to = t >> 4;         // 16 p-lanes x 16 o-groups
  const float* wrow[6];
  #pragma unroll
  for (int i=0;i<6;i++){
    int o = to*6 + i;                   // th/ph rows 0-63 are contiguous at wf+0
    wrow[i] = wf + (o < 64 ? o*CC : O_GXSW + (o-64)*CC);
  }
  float4 acc[6];
  #pragma unroll
  for (int i=0;i<6;i++) acc[i] = make_float4(0.f,0.f,0.f,0.f);
  __syncthreads();

  int px = tp*4;
  for (int c=0;c<CC;c+=4){
    float4 x0 = *(const float4*)(Xl + (c+0)*64 + px);
    float4 x1 = *(const float4*)(Xl + (c+1)*64 + px);
    float4 x2 = *(const float4*)(Xl + (c+2)*64 + px);
    float4 x3 = *(const float4*)(Xl + (c+3)*64 + px);
    #pragma unroll
    for (int i=0;i<6;i++){
      float4 wv = *(const float4*)(wrow[i] + c);
      acc[i].x += wv.x*x0.x + wv.y*x1.x + wv.z*x2.x + wv.w*x3.x;
      acc[i].y += wv.x*x0.y + wv.y*x1.y + wv.z*x2.y + wv.w*x3.y;
      acc[i].z += wv.x*x0.z + wv.y*x1.z + wv.z*x2.z + wv.w*x3.z;
      acc[i].w += wv.x*x0.w + wv.y*x1.w + wv.z*x2.w + wv.w*x3.w;
    }
  }

  #pragma unroll
  for (int i=0;i<6;i++){
    int o = to*6 + i;
    float sc, sh;
    if (o < 32)      { sc = wf[O_THS+o];     sh = wf[O_THB+o]; }
    else if (o < 64) { sc = wf[O_PHS+o-32];  sh = wf[O_PHB+o-32]; }
    else             { sc = wf[O_GXSS+o-64]; sh = wf[O_GXSB+o-64]; }
    float4 r;
    r.x = fmaxf(sc*acc[i].x + sh, 0.f);
    r.y = fmaxf(sc*acc[i].y + sh, 0.f);
    r.z = fmaxf(sc*acc[i].z + sh, 0.f);
    r.w = fmaxf(sc*acc[i].w + sh, 0.f);
    int p = p0 + px;
    if (o < 64){
      if (p < HW){
        unsigned int lo = (unsigned)f2hb(r.x) | ((unsigned)f2hb(r.y)<<16);
        unsigned int hi = (unsigned)f2hb(r.z) | ((unsigned)f2hb(r.w)<<16);
        *(uint2*)(thph + ((size_t)b*64 + o)*HW + p) = make_uint2(lo, hi);
      }
    } else {
      *(float4*)(Gp + (o-64)*GPS + px) = r;
    }
  }
  __syncthreads();
  if (t < 64){
    float g = 0.f;
    #pragma unroll
    for (int o=0;o<32;o++) g += Gp[o*GPS + t];
    int p = p0 + t;
    if (p < HW) g_xs[(size_t)b*HW + p] = g*(1.f/32.f);
  }
}

// ---- k3 v3 (R10, MFMA): Aphi[b,o,c] = sum_j wggs[0][o,j]*phi[b,c,j];
//      Atheta with wggs[1]/theta. Grid: which(2) x b(64) x M-half(2).
#define K3ST 40
__global__ __launch_bounds__(256) void k3_mfma(const unsigned short* wggs,
    const unsigned short* thph, float* Aphi, float* Atheta)
{
  __shared__ __align__(16) unsigned short Al[112*K3ST];
  __shared__ __align__(16) unsigned short Bl[32*K3ST];
  int t = threadIdx.x;
  int mh = blockIdx.x & 1;
  int b  = (blockIdx.x >> 1) & 63;
  int which = blockIdx.x >> 7;
  int m0 = mh*112;
  const unsigned short* wsrc = wggs + (size_t)which*IS*HW;
  const unsigned short* ssrc = thph + ((size_t)b*64 + (which ? 0 : 32))*HW;
  int lane = t & 63, w = t >> 6;
  int m16 = lane & 15, kq = lane >> 4;
  fragf4 acc[2][2];
  #pragma unroll
  for (int i=0;i<2;i++)
    #pragma unroll
    for (int nt=0;nt<2;nt++)
      #pragma unroll
      for (int r=0;r<4;r++) acc[i][nt][r] = 0.f;

  for (int kk=0; kk<25; kk++){
    int p0 = kk*32;
    __syncthreads();
    for (int i=t; i<112*4; i+=256){
      int row = i>>2, q = i&3;
      uint4 v = make_uint4(0u,0u,0u,0u);
      int gr = m0 + row, p = p0 + q*8;
      if (gr < IS && p+8 <= HW)
        v = *(const uint4*)(wsrc + (size_t)gr*HW + p);
      *(uint4*)(Al + row*K3ST + q*8) = v;
    }
    if (t < 128){
      int row = t>>2, q = t&3;
      uint4 v = make_uint4(0u,0u,0u,0u);
      int p = p0 + q*8;
      if (p+8 <= HW)
        v = *(const uint4*)(ssrc + (size_t)row*HW + p);
      *(uint4*)(Bl + row*K3ST + q*8) = v;
    }
    __syncthreads();
    short8 bfr[2];
    #pragma unroll
    for (int nt=0;nt<2;nt++)
      bfr[nt] = *(const short8*)(Bl + (nt*16+m16)*K3ST + kq*8);
    #pragma unroll
    for (int i=0;i<2;i++){
      int mt = w + 4*i;
      if (mt < 7){
        short8 af = *(const short8*)(Al + (mt*16+m16)*K3ST + kq*8);
        acc[i][0] = __builtin_amdgcn_mfma_f32_16x16x32_bf16(af, bfr[0], acc[i][0], 0,0,0);
        acc[i][1] = __builtin_amdgcn_mfma_f32_16x16x32_bf16(af, bfr[1], acc[i][1], 0,0,0);
      }
    }
  }
  float* dst = which ? Atheta : Aphi;
  #pragma unroll
  for (int i=0;i<2;i++){
    int mt = w + 4*i;
    if (mt >= 7) continue;
    #pragma unroll
    for (int r=0;r<4;r++){
      int o = m0 + mt*16 + kq*4 + r;
      if (o >= IS) continue;
      #pragma unroll
      for (int nt=0;nt<2;nt++){
        int c = nt*16 + m16;
        dst[((size_t)b*IS + o)*IC + c] = acc[i][nt][r];
      }
    }
  }
}

// ---- k4 v7 (MFMA): fused spatial chain per (b, 64-p tile).
#define ALS 33    // Al/Sl u32 stride
#define GTS 113   // Gt u32 stride (226 u16)
union K4Sh {
  struct { unsigned int Al[208*ALS]; unsigned int Sl[64*ALS]; } s1;
  unsigned int Gt[64*GTS];
};
__global__ __launch_bounds__(256,3) void k4_mfma(const void* x, const int* flagp,
    const float* wf, const unsigned short* thph,
    const float* Aphi, const float* Atheta, const float* g_xs,
    const unsigned int* ws1bf32, unsigned short* x1tp)
{
  __shared__ K4Sh sh;
  __shared__ float ash[64];
  int flag = *flagp;
  int t = threadIdx.x;
  int pt = blockIdx.x % 13, b = blockIdx.x / 13;
  int p0 = pt*64;
  int lane = t & 63, w = t >> 6;
  int col = lane & 15, kq = lane >> 4;

  const float* Ab = Aphi   + (size_t)b*IS*IC;
  const float* Tb = Atheta + (size_t)b*IS*IC;
  for (int i=t; i<208*32; i+=256){
    int o = i>>5, cp = i&31;
    unsigned int v = 0u;
    if (o < IS){
      const float* src = (cp<16 ? Ab : Tb) + o*IC + (cp&15)*2;
      v = (unsigned)f2hb(src[0]) | ((unsigned)f2hb(src[1])<<16);
    }
    sh.s1.Al[o*ALS + cp] = v;
  }
  const unsigned short* tb = thph + (size_t)b*64*HW;
  for (int i=t; i<32*64; i+=256){
    int c2 = i>>6, pp = i&63;
    int p = p0+pp;
    unsigned int v = 0u;
    if (p < HW){
      int c = c2*2;
      v = (unsigned)tb[(size_t)c*HW + p] | ((unsigned)tb[(size_t)(c+1)*HW + p]<<16);
    }
    sh.s1.Sl[pp*ALS + c2] = v;
  }
  __syncthreads();

  fragf4 acc1[13];
  #pragma unroll
  for (int nt=0; nt<13; nt++)
    #pragma unroll
    for (int r=0;r<4;r++) acc1[nt][r] = 0.f;
  #pragma unroll
  for (int kk=0; kk<2; kk++){
    FragU af;
    #pragma unroll
    for (int q=0;q<4;q++) af.w[q] = sh.s1.Sl[(w*16+col)*ALS + kk*16 + kq*4 + q];
    #pragma unroll
    for (int nt=0; nt<13; nt++){
      FragU bf;
      #pragma unroll
      for (int q=0;q<4;q++) bf.w[q] = sh.s1.Al[(nt*16+col)*ALS + kk*16 + kq*4 + q];
      acc1[nt] = __builtin_amdgcn_mfma_f32_16x16x32_bf16(af.s8, bf.s8, acc1[nt], 0,0,0);
    }
  }
  __syncthreads();   // Al/Sl dead; Gt aliases them

  unsigned short* Gt16 = (unsigned short*)sh.Gt;
  for (int i=t; i<64*9; i+=256){
    int pp = i/9, q = i - pp*9;
    sh.Gt[pp*GTS + 104 + q] = 0u;
  }
  if (t < 64){
    int p = p0 + t;
    float gx = (p < HW) ? g_xs[b*HW + p] : 0.f;
    Gt16[t*226 + 0] = f2hb(gx);
  }
  #pragma unroll
  for (int nt=0; nt<13; nt++){
    int o = nt*16 + col;
    float sc = wf[O_GGSS + o], shf = wf[O_GGSB + o];
    #pragma unroll
    for (int r=0;r<4;r++){
      int pp = w*16 + kq*4 + r;
      float g = fmaxf(sc*acc1[nt][r] + shf, 0.f);
      Gt16[pp*226 + 1 + o] = f2hb(g);
    }
  }
  __syncthreads();

  fragf4 acc2[4];
  #pragma unroll
  for (int nt=0; nt<4; nt++)
    #pragma unroll
    for (int r=0;r<4;r++) acc2[nt][r] = 0.f;
  #pragma unroll
  for (int kk=0; kk<7; kk++){
    FragU af;
    #pragma unroll
    for (int q=0;q<4;q++) af.w[q] = sh.Gt[(w*16+col)*GTS + kk*16 + kq*4 + q];
    #pragma unroll
    for (int nt=0; nt<4; nt++){
      FragU bf;
      #pragma unroll
      for (int q=0;q<4;q++) bf.w[q] = ws1bf32[(nt*16+col)*112 + kk*16 + kq*4 + q];
      acc2[nt] = __builtin_amdgcn_mfma_f32_16x16x32_bf16(af.s8, bf.s8, acc2[nt], 0,0,0);
    }
  }

  float wys[4] = {0.f,0.f,0.f,0.f};
  #pragma unroll
  for (int nt=0; nt<4; nt++){
    int o2 = nt*16 + col;
    bool vd = (o2 < DS);
    float s1 = vd ? wf[O_WS1S+o2] : 0.f;
    float b1 = vd ? wf[O_WS1B+o2] : 0.f;
    float w2 = vd ? wf[O_WS2W+o2] : 0.f;
    #pragma unroll
    for (int r=0;r<4;r++){
      float z = fmaxf(s1*acc2[nt][r] + b1, 0.f);
      wys[r] += w2*z;
    }
  }
  #pragma unroll
  for (int m=1; m<16; m<<=1){
    #pragma unroll
    for (int r=0;r<4;r++) wys[r] += __shfl_xor(wys[r], m, 16);
  }
  if (col == 0){
    float s2 = wf[O_WS2S], b2 = wf[O_WS2B];
    #pragma unroll
    for (int r=0;r<4;r++){
      int pp = w*16 + kq*4 + r;
      ash[pp] = sigf(s2*wys[r] + b2);
    }
  }
  __syncthreads();

  for (int i=t; i<CC*64; i+=256){
    int c = i>>6, pp = i&63;
    int p = p0 + pp;
    if (p < HW){
      float v = ash[pp]*loadx(x, flag, (size_t)b*CC*HW + (size_t)c*HW + p);
      x1tp[(size_t)b*CC*HW + (size_t)c*HW + p] = f2hb(v);
    }
  }
}

// ---- k8 v3 (R11, MFMA): out[g,c] = relu(sc*(sum_p Wall[g,p]*x1[b,p,c])+sh)
// for g in [0,588) over merged {thc,phc,gxc} weights. Grid: 13 M-tiles x 64 b.
#define KST 40
__global__ __launch_bounds__(256) void k8_mfma(const unsigned short* wbf,
    const unsigned short* x1tp, const float* wf, float* outp)
{
  __shared__ __align__(16) unsigned short Al[48*KST];
  __shared__ __align__(16) unsigned short Bl[128*KST];
  int t = threadIdx.x;
  int j = blockIdx.x & 63;
  int b = (j&7)*8 + (j>>3);
  int mt = blockIdx.x >> 6;          // 0..12
  int m0 = mt*48;
  const unsigned short* xsrc = x1tp + (size_t)b*CC*HW;
  int lane = t & 63, w = t >> 6;
  int m16 = lane & 15, kq = lane >> 4;
  fragf4 acc[3][2];
  #pragma unroll
  for (int st=0; st<3; st++)
    #pragma unroll
    for (int ct=0; ct<2; ct++)
      #pragma unroll
      for (int r=0; r<4; r++) acc[st][ct][r] = 0.f;

  for (int kk=0; kk<25; kk++){
    int p0 = kk*32;
    __syncthreads();
    if (t < 192){
      int row = t>>2, q = t&3;
      uint4 v = make_uint4(0u,0u,0u,0u);
      int g = m0 + row, p = p0 + q*8;
      if (g < 3*IS && p+8 <= HW)
        v = *(const uint4*)(wbf + (size_t)g*HW + p);
      *(uint4*)(Al + row*KST + q*8) = v;
    }
    for (int i=t; i<128*4; i+=256){
      int row = i>>2, q = i&3;
      uint4 v = make_uint4(0u,0u,0u,0u);
      int p = p0 + q*8;
      if (p+8 <= HW)
        v = *(const uint4*)(xsrc + (size_t)row*HW + p);
      *(uint4*)(Bl + row*KST + q*8) = v;
    }
    __syncthreads();
    short8 bfr[2];
    #pragma unroll
    for (int ct=0; ct<2; ct++){
      int n = (w*2+ct)*16 + m16;
      bfr[ct] = *(const short8*)(Bl + n*KST + kq*8);
    }
    #pragma unroll
    for (int st=0; st<3; st++){
      short8 af = *(const short8*)(Al + (st*16+m16)*KST + kq*8);
      acc[st][0] = __builtin_amdgcn_mfma_f32_16x16x32_bf16(af, bfr[0], acc[st][0], 0,0,0);
      acc[st][1] = __builtin_amdgcn_mfma_f32_16x16x32_bf16(af, bfr[1], acc[st][1], 0,0,0);
    }
  }
  #pragma unroll
  for (int st=0; st<3; st++){
    #pragma unroll
    for (int r=0; r<4; r++){
      int g = m0 + st*16 + kq*4 + r;
      if (g >= 3*IS) continue;
      int which = (g >= 2*IS) ? 2 : (g >= IS ? 1 : 0);
      int s = g - which*IS;
      int so = (which==2) ? O_GXCS : O_THCS + which*392;
      float sc = wf[so + s], sh = wf[so + 196 + s];
      float* dst = outp + (size_t)which*(64*IS*CC) + ((size_t)b*IS + s)*CC;
      #pragma unroll
      for (int ct=0; ct<2; ct++){
        int c = (w*2+ct)*16 + m16;
        dst[c] = fmaxf(sc*acc[st][ct][r] + sh, 0.f);
      }
    }
  }
}

// ---- k9 v2 (R12): Bph[b,s,o]=sum_j ggc_w[o,j]*phc[b,s,j]; Bth with thc.
// Weights transposed+float4-chunked into LDS: wtl[jc][o] holds float4
// w[o][4jc..4jc+3] at offset (jc*32+o)*4 -> lane o reads consecutive 16B
// (conflict-free ds_read_b128). src rows broadcast across 32 o-lanes.
// Each thread carries ~6 s-rows through one jc loop (6x wt reuse).
// Same sequential float4 accumulation order as v1 -> bit-identical.
__global__ __launch_bounds__(256) void k9_bfact(const float* wf, const float* thcp,
    const float* phcp, float* Bph, float* Bth)
{
  __shared__ __align__(16) float wtl[32*32*4];   // 16 KB
  int t = threadIdx.x;
  int sq = blockIdx.x & 3;
  int b  = (blockIdx.x >> 2) & 63;
  int which = blockIdx.x >> 8;
  for (int i = t; i < 32*32; i += 256){
    int jc = i >> 5, o = i & 31;
    *(float4*)(wtl + i*4) =
        *(const float4*)(wf + O_GGCW + o*256 + which*CC + jc*4);
  }
  __syncthreads();
  const float* src = which ? thcp : phcp;
  float* dst = which ? Bth : Bph;
  int o = t & 31, sloc = t >> 5;
  int s0 = sq*49;
  float acc[7];
  #pragma unroll
  for (int k=0;k<7;k++) acc[k]=0.f;
  const float* srow[7];
  #pragma unroll
  for (int k=0;k<7;k++){
    int sl = sloc + 8*k;
    srow[k] = src + ((size_t)b*IS + s0 + (sl<49 ? sl : 0))*CC;
  }
  for (int jc=0; jc<32; jc++){
    float4 wv = *(const float4*)(wtl + (jc*32+o)*4);
    #pragma unroll
    for (int k=0;k<7;k++){
      if (sloc + 8*k < 49){
        float4 sv = *(const float4*)(srow[k] + jc*4);
        acc[k] += wv.x*sv.x + wv.y*sv.y + wv.z*sv.z + wv.w*sv.w;
      }
    }
  }
  #pragma unroll
  for (int k=0;k<7;k++){
    int sl = sloc + 8*k;
    if (sl < 49){
      dst[((size_t)b*IS + s0 + sl)*IC + o] = acc[k];
    }
  }
}

// ---- k10a: s-chunk partial accumulation. Grid (b x 14 chunks), thread (d, o-half).
// part[b][sc][32o][128d]; gxp[b][sc][128d] (o-half 0 only).
__global__ __launch_bounds__(256) void k10a_part(const float* thcp, const float* phcp,
    const float* gxcp, const float* Bph, const float* Bth,
    float* part, float* gxp)
{
  int t = threadIdx.x;
  int d = t & 127, oh = t >> 7;
  int sc = blockIdx.x % 14, b = blockIdx.x / 14;
  int s0 = sc*14;
  float acc[16];
  #pragma unroll
  for (int o=0;o<16;o++) acc[o]=0.f;
  float gxa = 0.f;
  for (int i=0;i<14;i++){
    int s = s0 + i;
    size_t base = ((size_t)b*IS + s)*CC + d;
    float tv = thcp[base], pv = phcp[base];
    if (oh == 0) gxa += gxcp[base];
    const float* bp = Bph + ((size_t)b*IS + s)*IC + oh*16;
    const float* bt = Bth + ((size_t)b*IS + s)*IC + oh*16;
    #pragma unroll
    for (int o=0;o<16;o++) acc[o] += bp[o]*tv + bt[o]*pv;
  }
  float* pb = part + (((size_t)b*14 + sc)*IC + oh*16)*CC + d;
  #pragma unroll
  for (int o=0;o<16;o++) pb[(size_t)o*CC] = acc[o];
  if (oh == 0) gxp[((size_t)b*14 + sc)*CC + d] = gxa;
}

// ---- k10b: reduce 14 chunks + wc1/wc2/sigmoid epilogue -> c_att[b,d]
__global__ void k10b_catt(const float* wf, const float* part, const float* gxp,
                          float* c_att)
{
  int idx = blockIdx.x*256 + threadIdx.x;    // 64*128 exact
  int d = idx & 127;
  int b = idx >> 7;
  float acc[IC];
  #pragma unroll
  for (int o=0;o<IC;o++) acc[o]=0.f;
  float gx = 0.f;
  for (int sc=0; sc<14; sc++){
    gx += gxp[((size_t)b*14 + sc)*CC + d];
    const float* pb = part + ((size_t)b*14 + sc)*IC*CC + d;
    #pragma unroll
    for (int o=0;o<IC;o++) acc[o] += pb[(size_t)o*CC];
  }
  gx *= (1.f/196.f);
  #pragma unroll
  for (int o=0;o<IC;o++) acc[o] = fmaxf(wf[O_GGCS+o]*acc[o]+wf[O_GGCB+o], 0.f);
  float acc2 = 0.f;
  #pragma unroll
  for (int o2=0;o2<8;o2++){
    float tt = wf[O_WC1W + o2*33]*gx;
    #pragma unroll
    for (int o=0;o<IC;o++) tt += wf[O_WC1W + o2*33+1+o]*acc[o];
    float z = fmaxf(wf[O_WC1S+o2]*tt + wf[O_WC1B+o2], 0.f);
    acc2 += wf[O_WC2W+o2]*z;
  }
  c_att[idx] = sigf(wf[O_WC2S]*acc2 + wf[O_WC2B]);
}

// ---- k12 v2: out[b,c,p] = c_att[b,c]*x1tp[b,c,p] — pure streaming
__global__ void k12_final(const int* flagp, const unsigned int* x1tp2,
                          const float* c_att, void* out)
{
  int i = blockIdx.x*256 + threadIdx.x;      // over BB*CC*HW/2 uints, exact
  int flag = *flagp;
  unsigned int v = x1tp2[i];
  float a = c_att[i/392];                    // 392 uints per (b,c) row
  float v0 = a*hb2f((unsigned short)(v & 0xffff));
  float v1 = a*hb2f((unsigned short)(v >> 16));
  if (flag){
    ((unsigned int*)out)[i] = (unsigned)f2hb(v0) | ((unsigned)f2hb(v1)<<16);
  } else {
    ((float*)out)[2*i+0] = v0;
    ((float*)out)[2*i+1] = v1;
  }
}

extern "C" void kernel_launch(void* const* d_in, const int* in_sizes, int n_in,
                              void* d_out, int out_size, void* d_ws, size_t ws_size,
                              hipStream_t stream)
{
  const void* x = d_in[0];

  float* W = (float*)d_ws;
  int*   flag  = (int*)W;                    // W[0..63] reserved
  float* wf    = W + 64;                     // 800768
  float* theta = wf + WF_TOTAL;              // 1605632 (scratch; part alias)
  unsigned short* thph = (unsigned short*)(theta + 1605632); // 3211264 u16 (old phi slot)
  float* g_xs  = theta + 2*1605632;          // 50176
  float* Aphi  = g_xs + 50176;               // 401408
  float* Atheta= Aphi + 401408;              // 401408
  unsigned short* x1tp = (unsigned short*)(Atheta + 401408); // 6422528 u16 = 3211264 f32 slots
  float* thcp  = Atheta + 401408 + 3211264;  // 1605632
  float* phcp  = thcp + 1605632;             // 1605632
  float* gxcp  = phcp + 1605632;             // 1605632 (thcp/phcp/gxcp contiguous!)
  float* Bph   = gxcp + 1605632;             // 401408
  float* Bth   = Bph + 401408;               // 401408
  unsigned int* ws1bf32 = (unsigned int*)(Bth + 401408);  // 7168 u32 (slot 9664)
  float* c_att = (float*)(ws1bf32) + 9664;   // 8192
  unsigned short* wbf = (unsigned short*)(c_att + 8192);  // 768320 u16 (~53.8 MiB total)
  unsigned short* wggs = wbf + 3*IS*HW;      // 2*196*784 u16 (tail of wbf)
  // k10 partials reuse dead theta..Atheta region (4,064,256 contiguous floats):
  float* part = theta;                       // 64*14*32*128 = 3,670,016
  float* gxp  = theta + 3670016;             // 64*14*128  = 114,688 (fits: 3,784,704 < 4,064,256)

  ConvArgs ca;
  ca.cum[0] = 0;
  for (int i=0;i<36;i++){
    ca.p[i] = d_in[i+1];
    ca.cum[i+1] = ca.cum[i] + SRC_SIZES[i];
    ca.dst[i] = DST_OFF[i];
  }

  kd_detect<<<1, 256, 0, stream>>>(x, flag);
  kc_convert<<<(800716+255)/256, 256, 0, stream>>>(ca, flag, wf);
  kw_wbf<<<(5*IS*HW+255)/256, 256, 0, stream>>>(wf, wbf);
  k0_ws1bf<<<(64*112+255)/256, 256, 0, stream>>>(wf, ws1bf32);
  k1k2_tile<<<64*13, 256, 0, stream>>>(x, flag, wf, thph, g_xs);
  k3_mfma<<<2*64*2, 256, 0, stream>>>(wggs, thph, Aphi, Atheta);
  k4_mfma<<<64*13, 256, 0, stream>>>(x, flag, wf, thph, Aphi, Atheta,
      g_xs, ws1bf32, x1tp);
  k8_mfma<<<13*64, 256, 0, stream>>>(wbf, x1tp, wf, thcp);
  k9_bfact<<<2*64*4, 256, 0, stream>>>(wf, thcp, phcp, Bph, Bth);
  k10a_part<<<64*14, 256, 0, stream>>>(thcp, phcp, gxcp, Bph, Bth, part, gxp);
  k10b_catt<<<(BB*CC)/256, 256, 0, stream>>>(wf, part, gxp, c_att);
  k12_final<<<(BB*CC*HW/2)/256, 256, 0, stream>>>(flag, (const unsigned int*)x1tp,
      c_att, d_out);
}

// Round 5
// 346.048 us; speedup vs baseline: 1.6205x; 1.0547x over previous
//
#include <hip/hip_runtime.h>
#include <hip/hip_bf16.h>
#include <math.h>

// RGA module: B=64, C=128, HW=784, IC=32, IS=196, DS=49, DC=8.
// Rank-32 factorization removes Gs [b,784,784] and Gc [b,128,128] entirely.
// R5: k8 on MFMA. R7: k4 spatial chain fully on MFMA.
// R8: k10 split into s-chunk partials (896 blocks) + reduce.
// R9: k1+k2 fused into one LDS-tiled f32 GEMM (k1k2_tile).
// R10: k3 ported to the k8 MFMA template; theta/phi stored bf16 (thph).
// R11: k8 re-gridded (3 'which' GEMMs merged, 832 blocks, XCD-swizzled b).
// R12: k9 rebuilt (LDS-transposed weights, 60.5us -> ~8us).
// R13: k1k2 ported to MFMA. Old: f32 VALU GEMM at 16% of f32 peak, 45us,
//      41.5KB LDS capped occupancy at 3 blocks/CU. New: A=wthph[96][128] bf16
//      read straight from global (24KB, L1-resident); x staged TRANSPOSED to
//      LDS bf16 Xl[p][c] (stride 68 u32 -> aligned b128); 24 MFMA/wave;
//      gxs mean via shfl_xor over kq lanes. bf16 inputs bit-identical to old
//      path (only f32 sum order changes). LDS 17.4KB.

#define BB 64
#define CC 128
#define HW 784
#define IC 32
#define IS 196
#define DS 49

// ---- wf (converted f32 inputs) offsets, padded to 4-float alignment ----
#define O_THW 0
#define O_PHW 4096
#define O_GGSW 8192
#define O_GXSW 315520
#define O_WS1W 319616
#define O_WS2W 329272
#define O_THCW 329324
#define O_PHCW 482988
#define O_GGCW 636652
#define O_GXCW 644844
#define O_WC1W 798508
#define O_WC2W 798772
#define O_THS 798780
#define O_THB 798812
#define O_PHS 798844
#define O_PHB 798876
#define O_GGSS 798908
#define O_GGSB 799104
#define O_GXSS 799300
#define O_GXSB 799332
#define O_WS1S 799364
#define O_WS1B 799416
#define O_WS2S 799468
#define O_WS2B 799472
#define O_THCS 799476
#define O_THCB 799672
#define O_PHCS 799868
#define O_PHCB 800064
#define O_GGCS 800260
#define O_GGCB 800292
#define O_GXCS 800324
#define O_GXCB 800520
#define O_WC1S 800716
#define O_WC1B 800724
#define O_WC2S 800732
#define O_WC2B 800736
#define WF_TOTAL 800768

static const int SRC_SIZES[36] = {
  4096,4096,307328,4096,9653,49,153664,153664,8192,153664,264,8,
  32,32,32,32,196,196,32,32,49,49,1,1,196,196,196,196,32,32,196,196,8,8,1,1};
static const int DST_OFF[36] = {
  O_THW,O_PHW,O_GGSW,O_GXSW,O_WS1W,O_WS2W,O_THCW,O_PHCW,O_GGCW,O_GXCW,O_WC1W,O_WC2W,
  O_THS,O_THB,O_PHS,O_PHB,O_GGSS,O_GGSB,O_GXSS,O_GXSB,O_WS1S,O_WS1B,O_WS2S,O_WS2B,
  O_THCS,O_THCB,O_PHCS,O_PHCB,O_GGCS,O_GGCB,O_GXCS,O_GXCB,O_WC1S,O_WC1B,O_WC2S,O_WC2B};

struct ConvArgs { const void* p[36]; int cum[37]; int dst[36]; };

typedef __attribute__((ext_vector_type(8))) short short8;   // 8 bf16 (4 VGPRs)
typedef __attribute__((ext_vector_type(4))) float fragf4;   // MFMA C/D

union FragU { unsigned int w[4]; short8 s8; };

__device__ __forceinline__ float sigf(float v){ return 1.0f/(1.0f+expf(-v)); }
__device__ __forceinline__ float hb2f(unsigned short h){ return __uint_as_float(((unsigned)h)<<16); }
__device__ __forceinline__ unsigned short f2hb(float v){
  __hip_bfloat16 hb = __float2bfloat16(v);
  return *reinterpret_cast<unsigned short*>(&hb);
}
__device__ __forceinline__ float loadx(const void* x, int flag, size_t idx){
  if (flag) return hb2f(((const unsigned short*)x)[idx]);
  return ((const float*)x)[idx];
}

// ---- kd: dtype probe. bf16 data -> ~all sane exponents; f32-misread -> ~62%.
__global__ void kd_detect(const void* x, int* flag){
  __shared__ int cnt[256];
  int t = threadIdx.x;
  const unsigned short* h = (const unsigned short*)x;
  int c = 0;
  for (int k=0;k<4;k++){
    unsigned short v = h[t*4+k];
    int e = (v>>7)&0xFF;
    c += (e==0 || (e>=97 && e<=157)) ? 1 : 0;
  }
  cnt[t] = c;
  __syncthreads();
  for (int s=128; s; s>>=1){ if (t<s) cnt[t]+=cnt[t+s]; __syncthreads(); }
  if (t==0) *flag = (cnt[0] >= 973) ? 1 : 0;
}

// ---- kc: convert all non-x inputs to f32 arena wf
__global__ void kc_convert(ConvArgs a, const int* flagp, float* wf){
  int flag = *flagp;
  int g = blockIdx.x*256 + threadIdx.x;
  if (g >= a.cum[36]) return;
  int i = 0;
  while (g >= a.cum[i+1]) i++;
  int local = g - a.cum[i];
  float v;
  if (flag) v = hb2f(((const unsigned short*)a.p[i])[local]);
  else      v = ((const float*)a.p[i])[local];
  wf[a.dst[i] + local] = v;
}

// ---- kw: bf16 copies of thc/phc/gxc weights + ggs_w halves + wthph[96][128]
#define KW_TOT (5*IS*HW + 96*CC)
__global__ void kw_wbf(const float* wf, unsigned short* wbf){
  int i = blockIdx.x*256 + threadIdx.x;
  if (i >= KW_TOT) return;
  float v;
  if (i < 3*IS*HW){
    int which = i/(IS*HW), r = i - which*(IS*HW);
    int off = which==0?O_THCW:(which==1?O_PHCW:O_GXCW);
    v = wf[off + r];
  } else if (i < 5*IS*HW){
    int which = i/(IS*HW), r = i - which*(IS*HW);
    int row = r/HW, col = r - row*HW;
    v = wf[O_GGSW + row*(2*HW) + (which-3)*HW + col];
  } else {
    int r = i - 5*IS*HW;               // 0..12287
    int row = r >> 7, col = r & 127;   // th 0-31, ph 32-63 (contig at wf+0), gxs 64-95
    v = (row < 64) ? wf[row*CC + col] : wf[O_GXSW + (row-64)*CC + col];
  }
  wbf[i] = f2hb(v);
}

// ---- k0: ws1bf [64][224] bf16 (zero-padded W1aug: col0 = gx weight)
__global__ void k0_ws1bf(const float* wf, unsigned int* ws1bf32){
  int i = blockIdx.x*256 + threadIdx.x;      // 64*112 u32
  if (i >= 64*112) return;
  int o2 = i/112, k2 = i - o2*112;
  int k = k2*2;
  float v0 = (o2<DS && k<197)   ? wf[O_WS1W + o2*197 + k]   : 0.f;
  float v1 = (o2<DS && k+1<197) ? wf[O_WS1W + o2*197 + k+1] : 0.f;
  ws1bf32[i] = (unsigned)f2hb(v0) | ((unsigned)f2hb(v1)<<16);
}

// ---- k1k2 v3 (R13, MFMA): theta/phi/g_xs projections.
// D[o][p] = sum_c W[o][c]*x[b][c][p]. A-frags from global wthph (L1-resident);
// B-frags from LDS Xl[p][c] bf16 (transposed at staging). Wave w owns p-tile
// w*16; 6 m-tiles x 4 k-steps = 24 MFMA/wave. Rows 64-95 = gxs -> relu+mean.
#define XST 68   // Xl u32 stride per p-row (272B: 16B-aligned b128 reads)
__global__ __launch_bounds__(256) void k1k2_mfma(const void* x, const int* flagp,
    const float* wf, const unsigned short* wthph, unsigned short* thph, float* g_xs)
{
  __shared__ __align__(16) unsigned int Xl[64*XST];   // 17.4 KB
  int flag = *flagp;
  int t = threadIdx.x;
  int pt = blockIdx.x % 13, b = blockIdx.x / 13;
  int p0 = pt*64;

  // stage x^T tile: Xl[p][c] bf16 via 2x2 transpose micro-tiles (8 units/thread)
  #pragma unroll
  for (int k=0; k<8; k++){
    int idx = k*256 + t;
    int q = idx & 31;              // p-pair (coalesced across lanes)
    int c2 = idx >> 5;             // c-pair, 0..63
    int p = p0 + 2*q, c = 2*c2;
    unsigned int w0 = 0u, w1 = 0u;
    if (p < HW){                   // HW even, p even -> p+1 < HW too
      if (flag){
        const unsigned short* xb = (const unsigned short*)x + (size_t)b*CC*HW;
        unsigned int a0 = *(const unsigned int*)(xb + (size_t)c*HW + p);
        unsigned int a1 = *(const unsigned int*)(xb + (size_t)(c+1)*HW + p);
        w0 = (a0 & 0xffffu) | (a1 << 16);
        w1 = (a0 >> 16) | (a1 & 0xffff0000u);
      } else {
        const float* xb = (const float*)x + (size_t)b*CC*HW;
        float2 a0 = *(const float2*)(xb + (size_t)c*HW + p);
        float2 a1 = *(const float2*)(xb + (size_t)(c+1)*HW + p);
        w0 = (unsigned)f2hb(a0.x) | ((unsigned)f2hb(a1.x)<<16);
        w1 = (unsigned)f2hb(a0.y) | ((unsigned)f2hb(a1.y)<<16);
      }
    }
    Xl[(2*q+0)*XST + c2] = w0;
    Xl[(2*q+1)*XST + c2] = w1;
  }
  __syncthreads();

  int lane = t & 63, w = t >> 6;
  int m16 = lane & 15, kq = lane >> 4;
  fragf4 acc[6];
  #pragma unroll
  for (int mt=0; mt<6; mt++)
    #pragma unroll
    for (int r=0;r<4;r++) acc[mt][r] = 0.f;

  const unsigned short* Xu = (const unsigned short*)Xl;
  #pragma unroll
  for (int kk=0; kk<4; kk++){
    short8 bfr = *(const short8*)(Xu + (w*16+m16)*(2*XST) + kk*32 + kq*8);
    #pragma unroll
    for (int mt=0; mt<6; mt++){
      short8 af = *(const short8*)(wthph + (mt*16+m16)*CC + kk*32 + kq*8);
      acc[mt] = __builtin_amdgcn_mfma_f32_16x16x32_bf16(af, bfr, acc[mt], 0,0,0);
    }
  }

  int p = p0 + w*16 + m16;
  // theta/phi epilogue: o = mt*16 + kq*4 + r in [0,64)
  #pragma unroll
  for (int mt=0; mt<4; mt++){
    #pragma unroll
    for (int r=0;r<4;r++){
      int o = mt*16 + kq*4 + r;
      float sc = (o<32) ? wf[O_THS+o] : wf[O_PHS+o-32];
      float sh = (o<32) ? wf[O_THB+o] : wf[O_PHB+o-32];
      float v = fmaxf(sc*acc[mt][r] + sh, 0.f);
      if (p < HW) thph[((size_t)b*64 + o)*HW + p] = f2hb(v);
    }
  }
  // gxs epilogue: relu'd rows 64..95, mean over o via kq-lane reduce
  float gs = 0.f;
  #pragma unroll
  for (int mt=4; mt<6; mt++){
    #pragma unroll
    for (int r=0;r<4;r++){
      int o = (mt-4)*16 + kq*4 + r;
      gs += fmaxf(wf[O_GXSS+o]*acc[mt][r] + wf[O_GXSB+o], 0.f);
    }
  }
  gs += __shfl_xor(gs, 16);
  gs += __shfl_xor(gs, 32);
  if (kq == 0 && p < HW) g_xs[(size_t)b*HW + p] = gs*(1.f/32.f);
}

// ---- k3 v3 (R10, MFMA): Aphi[b,o,c] = sum_j wggs[0][o,j]*phi[b,c,j];
//      Atheta with wggs[1]/theta. Grid: which(2) x b(64) x M-half(2).
#define K3ST 40
__global__ __launch_bounds__(256) void k3_mfma(const unsigned short* wggs,
    const unsigned short* thph, float* Aphi, float* Atheta)
{
  __shared__ __align__(16) unsigned short Al[112*K3ST];
  __shared__ __align__(16) unsigned short Bl[32*K3ST];
  int t = threadIdx.x;
  int mh = blockIdx.x & 1;
  int b  = (blockIdx.x >> 1) & 63;
  int which = blockIdx.x >> 7;
  int m0 = mh*112;
  const unsigned short* wsrc = wggs + (size_t)which*IS*HW;
  const unsigned short* ssrc = thph + ((size_t)b*64 + (which ? 0 : 32))*HW;
  int lane = t & 63, w = t >> 6;
  int m16 = lane & 15, kq = lane >> 4;
  fragf4 acc[2][2];
  #pragma unroll
  for (int i=0;i<2;i++)
    #pragma unroll
    for (int nt=0;nt<2;nt++)
      #pragma unroll
      for (int r=0;r<4;r++) acc[i][nt][r] = 0.f;

  for (int kk=0; kk<25; kk++){
    int p0 = kk*32;
    __syncthreads();
    for (int i=t; i<112*4; i+=256){
      int row = i>>2, q = i&3;
      uint4 v = make_uint4(0u,0u,0u,0u);
      int gr = m0 + row, p = p0 + q*8;
      if (gr < IS && p+8 <= HW)
        v = *(const uint4*)(wsrc + (size_t)gr*HW + p);
      *(uint4*)(Al + row*K3ST + q*8) = v;
    }
    if (t < 128){
      int row = t>>2, q = t&3;
      uint4 v = make_uint4(0u,0u,0u,0u);
      int p = p0 + q*8;
      if (p+8 <= HW)
        v = *(const uint4*)(ssrc + (size_t)row*HW + p);
      *(uint4*)(Bl + row*K3ST + q*8) = v;
    }
    __syncthreads();
    short8 bfr[2];
    #pragma unroll
    for (int nt=0;nt<2;nt++)
      bfr[nt] = *(const short8*)(Bl + (nt*16+m16)*K3ST + kq*8);
    #pragma unroll
    for (int i=0;i<2;i++){
      int mt = w + 4*i;
      if (mt < 7){
        short8 af = *(const short8*)(Al + (mt*16+m16)*K3ST + kq*8);
        acc[i][0] = __builtin_amdgcn_mfma_f32_16x16x32_bf16(af, bfr[0], acc[i][0], 0,0,0);
        acc[i][1] = __builtin_amdgcn_mfma_f32_16x16x32_bf16(af, bfr[1], acc[i][1], 0,0,0);
      }
    }
  }
  float* dst = which ? Atheta : Aphi;
  #pragma unroll
  for (int i=0;i<2;i++){
    int mt = w + 4*i;
    if (mt >= 7) continue;
    #pragma unroll
    for (int r=0;r<4;r++){
      int o = m0 + mt*16 + kq*4 + r;
      if (o >= IS) continue;
      #pragma unroll
      for (int nt=0;nt<2;nt++){
        int c = nt*16 + m16;
        dst[((size_t)b*IS + o)*IC + c] = acc[i][nt][r];
      }
    }
  }
}

// ---- k4 v7 (MFMA): fused spatial chain per (b, 64-p tile).
#define ALS 33    // Al/Sl u32 stride
#define GTS 113   // Gt u32 stride (226 u16)
union K4Sh {
  struct { unsigned int Al[208*ALS]; unsigned int Sl[64*ALS]; } s1;
  unsigned int Gt[64*GTS];
};
__global__ __launch_bounds__(256,3) void k4_mfma(const void* x, const int* flagp,
    const float* wf, const unsigned short* thph,
    const float* Aphi, const float* Atheta, const float* g_xs,
    const unsigned int* ws1bf32, unsigned short* x1tp)
{
  __shared__ K4Sh sh;
  __shared__ float ash[64];
  int flag = *flagp;
  int t = threadIdx.x;
  int pt = blockIdx.x % 13, b = blockIdx.x / 13;
  int p0 = pt*64;
  int lane = t & 63, w = t >> 6;
  int col = lane & 15, kq = lane >> 4;

  const float* Ab = Aphi   + (size_t)b*IS*IC;
  const float* Tb = Atheta + (size_t)b*IS*IC;
  for (int i=t; i<208*32; i+=256){
    int o = i>>5, cp = i&31;
    unsigned int v = 0u;
    if (o < IS){
      const float* src = (cp<16 ? Ab : Tb) + o*IC + (cp&15)*2;
      v = (unsigned)f2hb(src[0]) | ((unsigned)f2hb(src[1])<<16);
    }
    sh.s1.Al[o*ALS + cp] = v;
  }
  const unsigned short* tb = thph + (size_t)b*64*HW;
  for (int i=t; i<32*64; i+=256){
    int c2 = i>>6, pp = i&63;
    int p = p0+pp;
    unsigned int v = 0u;
    if (p < HW){
      int c = c2*2;
      v = (unsigned)tb[(size_t)c*HW + p] | ((unsigned)tb[(size_t)(c+1)*HW + p]<<16);
    }
    sh.s1.Sl[pp*ALS + c2] = v;
  }
  __syncthreads();

  fragf4 acc1[13];
  #pragma unroll
  for (int nt=0; nt<13; nt++)
    #pragma unroll
    for (int r=0;r<4;r++) acc1[nt][r] = 0.f;
  #pragma unroll
  for (int kk=0; kk<2; kk++){
    FragU af;
    #pragma unroll
    for (int q=0;q<4;q++) af.w[q] = sh.s1.Sl[(w*16+col)*ALS + kk*16 + kq*4 + q];
    #pragma unroll
    for (int nt=0; nt<13; nt++){
      FragU bf;
      #pragma unroll
      for (int q=0;q<4;q++) bf.w[q] = sh.s1.Al[(nt*16+col)*ALS + kk*16 + kq*4 + q];
      acc1[nt] = __builtin_amdgcn_mfma_f32_16x16x32_bf16(af.s8, bf.s8, acc1[nt], 0,0,0);
    }
  }
  __syncthreads();   // Al/Sl dead; Gt aliases them

  unsigned short* Gt16 = (unsigned short*)sh.Gt;
  for (int i=t; i<64*9; i+=256){
    int pp = i/9, q = i - pp*9;
    sh.Gt[pp*GTS + 104 + q] = 0u;
  }
  if (t < 64){
    int p = p0 + t;
    float gx = (p < HW) ? g_xs[b*HW + p] : 0.f;
    Gt16[t*226 + 0] = f2hb(gx);
  }
  #pragma unroll
  for (int nt=0; nt<13; nt++){
    int o = nt*16 + col;
    float sc = wf[O_GGSS + o], shf = wf[O_GGSB + o];
    #pragma unroll
    for (int r=0;r<4;r++){
      int pp = w*16 + kq*4 + r;
      float g = fmaxf(sc*acc1[nt][r] + shf, 0.f);
      Gt16[pp*226 + 1 + o] = f2hb(g);
    }
  }
  __syncthreads();

  fragf4 acc2[4];
  #pragma unroll
  for (int nt=0; nt<4; nt++)
    #pragma unroll
    for (int r=0;r<4;r++) acc2[nt][r] = 0.f;
  #pragma unroll
  for (int kk=0; kk<7; kk++){
    FragU af;
    #pragma unroll
    for (int q=0;q<4;q++) af.w[q] = sh.Gt[(w*16+col)*GTS + kk*16 + kq*4 + q];
    #pragma unroll
    for (int nt=0; nt<4; nt++){
      FragU bf;
      #pragma unroll
      for (int q=0;q<4;q++) bf.w[q] = ws1bf32[(nt*16+col)*112 + kk*16 + kq*4 + q];
      acc2[nt] = __builtin_amdgcn_mfma_f32_16x16x32_bf16(af.s8, bf.s8, acc2[nt], 0,0,0);
    }
  }

  float wys[4] = {0.f,0.f,0.f,0.f};
  #pragma unroll
  for (int nt=0; nt<4; nt++){
    int o2 = nt*16 + col;
    bool vd = (o2 < DS);
    float s1 = vd ? wf[O_WS1S+o2] : 0.f;
    float b1 = vd ? wf[O_WS1B+o2] : 0.f;
    float w2 = vd ? wf[O_WS2W+o2] : 0.f;
    #pragma unroll
    for (int r=0;r<4;r++){
      float z = fmaxf(s1*acc2[nt][r] + b1, 0.f);
      wys[r] += w2*z;
    }
  }
  #pragma unroll
  for (int m=1; m<16; m<<=1){
    #pragma unroll
    for (int r=0;r<4;r++) wys[r] += __shfl_xor(wys[r], m, 16);
  }
  if (col == 0){
    float s2 = wf[O_WS2S], b2 = wf[O_WS2B];
    #pragma unroll
    for (int r=0;r<4;r++){
      int pp = w*16 + kq*4 + r;
      ash[pp] = sigf(s2*wys[r] + b2);
    }
  }
  __syncthreads();

  for (int i=t; i<CC*64; i+=256){
    int c = i>>6, pp = i&63;
    int p = p0 + pp;
    if (p < HW){
      float v = ash[pp]*loadx(x, flag, (size_t)b*CC*HW + (size_t)c*HW + p);
      x1tp[(size_t)b*CC*HW + (size_t)c*HW + p] = f2hb(v);
    }
  }
}

// ---- k8 v3 (R11, MFMA): out[g,c] = relu(sc*(sum_p Wall[g,p]*x1[b,p,c])+sh)
// for g in [0,588) over merged {thc,phc,gxc} weights. Grid: 13 M-tiles x 64 b.
#define KST 40
__global__ __launch_bounds__(256) void k8_mfma(const unsigned short* wbf,
    const unsigned short* x1tp, const float* wf, float* outp)
{
  __shared__ __align__(16) unsigned short Al[48*KST];
  __shared__ __align__(16) unsigned short Bl[128*KST];
  int t = threadIdx.x;
  int j = blockIdx.x & 63;
  int b = (j&7)*8 + (j>>3);
  int mt = blockIdx.x >> 6;          // 0..12
  int m0 = mt*48;
  const unsigned short* xsrc = x1tp + (size_t)b*CC*HW;
  int lane = t & 63, w = t >> 6;
  int m16 = lane & 15, kq = lane >> 4;
  fragf4 acc[3][2];
  #pragma unroll
  for (int st=0; st<3; st++)
    #pragma unroll
    for (int ct=0; ct<2; ct++)
      #pragma unroll
      for (int r=0; r<4; r++) acc[st][ct][r] = 0.f;

  for (int kk=0; kk<25; kk++){
    int p0 = kk*32;
    __syncthreads();
    if (t < 192){
      int row = t>>2, q = t&3;
      uint4 v = make_uint4(0u,0u,0u,0u);
      int g = m0 + row, p = p0 + q*8;
      if (g < 3*IS && p+8 <= HW)
        v = *(const uint4*)(wbf + (size_t)g*HW + p);
      *(uint4*)(Al + row*KST + q*8) = v;
    }
    for (int i=t; i<128*4; i+=256){
      int row = i>>2, q = i&3;
      uint4 v = make_uint4(0u,0u,0u,0u);
      int p = p0 + q*8;
      if (p+8 <= HW)
        v = *(const uint4*)(xsrc + (size_t)row*HW + p);
      *(uint4*)(Bl + row*KST + q*8) = v;
    }
    __syncthreads();
    short8 bfr[2];
    #pragma unroll
    for (int ct=0; ct<2; ct++){
      int n = (w*2+ct)*16 + m16;
      bfr[ct] = *(const short8*)(Bl + n*KST + kq*8);
    }
    #pragma unroll
    for (int st=0; st<3; st++){
      short8 af = *(const short8*)(Al + (st*16+m16)*KST + kq*8);
      acc[st][0] = __builtin_amdgcn_mfma_f32_16x16x32_bf16(af, bfr[0], acc[st][0], 0,0,0);
      acc[st][1] = __builtin_amdgcn_mfma_f32_16x16x32_bf16(af, bfr[1], acc[st][1], 0,0,0);
    }
  }
  #pragma unroll
  for (int st=0; st<3; st++){
    #pragma unroll
    for (int r=0; r<4; r++){
      int g = m0 + st*16 + kq*4 + r;
      if (g >= 3*IS) continue;
      int which = (g >= 2*IS) ? 2 : (g >= IS ? 1 : 0);
      int s = g - which*IS;
      int so = (which==2) ? O_GXCS : O_THCS + which*392;
      float sc = wf[so + s], sh = wf[so + 196 + s];
      float* dst = outp + (size_t)which*(64*IS*CC) + ((size_t)b*IS + s)*CC;
      #pragma unroll
      for (int ct=0; ct<2; ct++){
        int c = (w*2+ct)*16 + m16;
        dst[c] = fmaxf(sc*acc[st][ct][r] + sh, 0.f);
      }
    }
  }
}

// ---- k9 v2 (R12): Bph[b,s,o]=sum_j ggc_w[o,j]*phc[b,s,j]; Bth with thc.
__global__ __launch_bounds__(256) void k9_bfact(const float* wf, const float* thcp,
    const float* phcp, float* Bph, float* Bth)
{
  __shared__ __align__(16) float wtl[32*32*4];   // 16 KB
  int t = threadIdx.x;
  int sq = blockIdx.x & 3;
  int b  = (blockIdx.x >> 2) & 63;
  int which = blockIdx.x >> 8;
  for (int i = t; i < 32*32; i += 256){
    int jc = i >> 5, o = i & 31;
    *(float4*)(wtl + i*4) =
        *(const float4*)(wf + O_GGCW + o*256 + which*CC + jc*4);
  }
  __syncthreads();
  const float* src = which ? thcp : phcp;
  float* dst = which ? Bth : Bph;
  int o = t & 31, sloc = t >> 5;
  int s0 = sq*49;
  float acc[7];
  #pragma unroll
  for (int k=0;k<7;k++) acc[k]=0.f;
  const float* srow[7];
  #pragma unroll
  for (int k=0;k<7;k++){
    int sl = sloc + 8*k;
    srow[k] = src + ((size_t)b*IS + s0 + (sl<49 ? sl : 0))*CC;
  }
  for (int jc=0; jc<32; jc++){
    float4 wv = *(const float4*)(wtl + (jc*32+o)*4);
    #pragma unroll
    for (int k=0;k<7;k++){
      if (sloc + 8*k < 49){
        float4 sv = *(const float4*)(srow[k] + jc*4);
        acc[k] += wv.x*sv.x + wv.y*sv.y + wv.z*sv.z + wv.w*sv.w;
      }
    }
  }
  #pragma unroll
  for (int k=0;k<7;k++){
    int sl = sloc + 8*k;
    if (sl < 49){
      dst[((size_t)b*IS + s0 + sl)*IC + o] = acc[k];
    }
  }
}

// ---- k10a: s-chunk partial accumulation. Grid (b x 14 chunks), thread (d, o-half).
__global__ __launch_bounds__(256) void k10a_part(const float* thcp, const float* phcp,
    const float* gxcp, const float* Bph, const float* Bth,
    float* part, float* gxp)
{
  int t = threadIdx.x;
  int d = t & 127, oh = t >> 7;
  int sc = blockIdx.x % 14, b = blockIdx.x / 14;
  int s0 = sc*14;
  float acc[16];
  #pragma unroll
  for (int o=0;o<16;o++) acc[o]=0.f;
  float gxa = 0.f;
  for (int i=0;i<14;i++){
    int s = s0 + i;
    size_t base = ((size_t)b*IS + s)*CC + d;
    float tv = thcp[base], pv = phcp[base];
    if (oh == 0) gxa += gxcp[base];
    const float* bp = Bph + ((size_t)b*IS + s)*IC + oh*16;
    const float* bt = Bth + ((size_t)b*IS + s)*IC + oh*16;
    #pragma unroll
    for (int o=0;o<16;o++) acc[o] += bp[o]*tv + bt[o]*pv;
  }
  float* pb = part + (((size_t)b*14 + sc)*IC + oh*16)*CC + d;
  #pragma unroll
  for (int o=0;o<16;o++) pb[(size_t)o*CC] = acc[o];
  if (oh == 0) gxp[((size_t)b*14 + sc)*CC + d] = gxa;
}

// ---- k10b: reduce 14 chunks + wc1/wc2/sigmoid epilogue -> c_att[b,d]
__global__ void k10b_catt(const float* wf, const float* part, const float* gxp,
                          float* c_att)
{
  int idx = blockIdx.x*256 + threadIdx.x;    // 64*128 exact
  int d = idx & 127;
  int b = idx >> 7;
  float acc[IC];
  #pragma unroll
  for (int o=0;o<IC;o++) acc[o]=0.f;
  float gx = 0.f;
  for (int sc=0; sc<14; sc++){
    gx += gxp[((size_t)b*14 + sc)*CC + d];
    const float* pb = part + ((size_t)b*14 + sc)*IC*CC + d;
    #pragma unroll
    for (int o=0;o<IC;o++) acc[o] += pb[(size_t)o*CC];
  }
  gx *= (1.f/196.f);
  #pragma unroll
  for (int o=0;o<IC;o++) acc[o] = fmaxf(wf[O_GGCS+o]*acc[o]+wf[O_GGCB+o], 0.f);
  float acc2 = 0.f;
  #pragma unroll
  for (int o2=0;o2<8;o2++){
    float tt = wf[O_WC1W + o2*33]*gx;
    #pragma unroll
    for (int o=0;o<IC;o++) tt += wf[O_WC1W + o2*33+1+o]*acc[o];
    float z = fmaxf(wf[O_WC1S+o2]*tt + wf[O_WC1B+o2], 0.f);
    acc2 += wf[O_WC2W+o2]*z;
  }
  c_att[idx] = sigf(wf[O_WC2S]*acc2 + wf[O_WC2B]);
}

// ---- k12 v2: out[b,c,p] = c_att[b,c]*x1tp[b,c,p] — pure streaming
__global__ void k12_final(const int* flagp, const unsigned int* x1tp2,
                          const float* c_att, void* out)
{
  int i = blockIdx.x*256 + threadIdx.x;      // over BB*CC*HW/2 uints, exact
  int flag = *flagp;
  unsigned int v = x1tp2[i];
  float a = c_att[i/392];                    // 392 uints per (b,c) row
  float v0 = a*hb2f((unsigned short)(v & 0xffff));
  float v1 = a*hb2f((unsigned short)(v >> 16));
  if (flag){
    ((unsigned int*)out)[i] = (unsigned)f2hb(v0) | ((unsigned)f2hb(v1)<<16);
  } else {
    ((float*)out)[2*i+0] = v0;
    ((float*)out)[2*i+1] = v1;
  }
}

extern "C" void kernel_launch(void* const* d_in, const int* in_sizes, int n_in,
                              void* d_out, int out_size, void* d_ws, size_t ws_size,
                              hipStream_t stream)
{
  const void* x = d_in[0];

  float* W = (float*)d_ws;
  int*   flag  = (int*)W;                    // W[0..63] reserved
  float* wf    = W + 64;                     // 800768
  float* theta = wf + WF_TOTAL;              // 1605632 (scratch; part alias)
  unsigned short* thph = (unsigned short*)(theta + 1605632); // 3211264 u16 (old phi slot)
  float* g_xs  = theta + 2*1605632;          // 50176
  float* Aphi  = g_xs + 50176;               // 401408
  float* Atheta= Aphi + 401408;              // 401408
  unsigned short* x1tp = (unsigned short*)(Atheta + 401408); // 6422528 u16 = 3211264 f32 slots
  float* thcp  = Atheta + 401408 + 3211264;  // 1605632
  float* phcp  = thcp + 1605632;             // 1605632
  float* gxcp  = phcp + 1605632;             // 1605632 (thcp/phcp/gxcp contiguous!)
  float* Bph   = gxcp + 1605632;             // 401408
  float* Bth   = Bph + 401408;               // 401408
  unsigned int* ws1bf32 = (unsigned int*)(Bth + 401408);  // 7168 u32 (slot 9664)
  float* c_att = (float*)(ws1bf32) + 9664;   // 8192
  unsigned short* wbf = (unsigned short*)(c_att + 8192);  // 780608 u16 (~53.9 MiB total)
  unsigned short* wggs = wbf + 3*IS*HW;      // 2*196*784 u16
  unsigned short* wthph = wbf + 5*IS*HW;     // 96*128 u16 (tail of wbf)
  // k10 partials reuse dead theta..Atheta region (4,064,256 contiguous floats):
  float* part = theta;                       // 64*14*32*128 = 3,670,016
  float* gxp  = theta + 3670016;             // 64*14*128  = 114,688 (fits: 3,784,704 < 4,064,256)

  ConvArgs ca;
  ca.cum[0] = 0;
  for (int i=0;i<36;i++){
    ca.p[i] = d_in[i+1];
    ca.cum[i+1] = ca.cum[i] + SRC_SIZES[i];
    ca.dst[i] = DST_OFF[i];
  }

  kd_detect<<<1, 256, 0, stream>>>(x, flag);
  kc_convert<<<(800716+255)/256, 256, 0, stream>>>(ca, flag, wf);
  kw_wbf<<<(KW_TOT+255)/256, 256, 0, stream>>>(wf, wbf);
  k0_ws1bf<<<(64*112+255)/256, 256, 0, stream>>>(wf, ws1bf32);
  k1k2_mfma<<<64*13, 256, 0, stream>>>(x, flag, wf, wthph, thph, g_xs);
  k3_mfma<<<2*64*2, 256, 0, stream>>>(wggs, thph, Aphi, Atheta);
  k4_mfma<<<64*13, 256, 0, stream>>>(x, flag, wf, thph, Aphi, Atheta,
      g_xs, ws1bf32, x1tp);
  k8_mfma<<<13*64, 256, 0, stream>>>(wbf, x1tp, wf, thcp);
  k9_bfact<<<2*64*4, 256, 0, stream>>>(wf, thcp, phcp, Bph, Bth);
  k10a_part<<<64*14, 256, 0, stream>>>(thcp, phcp, gxcp, Bph, Bth, part, gxp);
  k10b_catt<<<(BB*CC)/256, 256, 0, stream>>>(wf, part, gxp, c_att);
  k12_final<<<(BB*CC*HW/2)/256, 256, 0, stream>>>(flag, (const unsigned int*)x1tp,
      c_att, d_out);
}

// Round 6
// 332.774 us; speedup vs baseline: 1.6851x; 1.0399x over previous
//
#include <hip/hip_runtime.h>
#include <hip/hip_bf16.h>
#include <math.h>

// RGA module: B=64, C=128, HW=784, IC=32, IS=196, DS=49, DC=8.
// Rank-32 factorization removes Gs [b,784,784] and Gc [b,128,128] entirely.
// R5: k8 on MFMA. R7: k4 spatial chain fully on MFMA.
// R8: k10 split into s-chunk partials (896 blocks) + reduce.
// R9: k1+k2 fused into one LDS-tiled f32 GEMM (k1k2_tile).
// R10: k3 ported to the k8 MFMA template; theta/phi stored bf16 (thph).
// R11: k8 re-gridded (3 'which' GEMMs merged, 832 blocks, XCD-swizzled b).
// R12: k9 rebuilt (LDS-transposed weights, 60.5us -> ~8us).
// R13: k1k2 ported to MFMA (45us -> ~12us).
// R14: k4 staging de-scalarized. k3 now emits acomb[b][208][64] bf16 in k4's
//      exact Al row layout (Aphi c0-31 | Atheta c0-31) -- k4's 13.3K scalar
//      f32 loads + converts/block become 1664 uint4 copies (LDS stride 72 u16,
//      16B-aligned, 2-way banks). Sl staging paired (u32 loads, 2x fewer);
//      x1 epilogue vectorized 4-wide (p<HW <=> p+4<=HW since p%4==0).
//      All bit-identical transformations.

#define BB 64
#define CC 128
#define HW 784
#define IC 32
#define IS 196
#define DS 49

// ---- wf (converted f32 inputs) offsets, padded to 4-float alignment ----
#define O_THW 0
#define O_PHW 4096
#define O_GGSW 8192
#define O_GXSW 315520
#define O_WS1W 319616
#define O_WS2W 329272
#define O_THCW 329324
#define O_PHCW 482988
#define O_GGCW 636652
#define O_GXCW 644844
#define O_WC1W 798508
#define O_WC2W 798772
#define O_THS 798780
#define O_THB 798812
#define O_PHS 798844
#define O_PHB 798876
#define O_GGSS 798908
#define O_GGSB 799104
#define O_GXSS 799300
#define O_GXSB 799332
#define O_WS1S 799364
#define O_WS1B 799416
#define O_WS2S 799468
#define O_WS2B 799472
#define O_THCS 799476
#define O_THCB 799672
#define O_PHCS 799868
#define O_PHCB 800064
#define O_GGCS 800260
#define O_GGCB 800292
#define O_GXCS 800324
#define O_GXCB 800520
#define O_WC1S 800716
#define O_WC1B 800724
#define O_WC2S 800732
#define O_WC2B 800736
#define WF_TOTAL 800768

static const int SRC_SIZES[36] = {
  4096,4096,307328,4096,9653,49,153664,153664,8192,153664,264,8,
  32,32,32,32,196,196,32,32,49,49,1,1,196,196,196,196,32,32,196,196,8,8,1,1};
static const int DST_OFF[36] = {
  O_THW,O_PHW,O_GGSW,O_GXSW,O_WS1W,O_WS2W,O_THCW,O_PHCW,O_GGCW,O_GXCW,O_WC1W,O_WC2W,
  O_THS,O_THB,O_PHS,O_PHB,O_GGSS,O_GGSB,O_GXSS,O_GXSB,O_WS1S,O_WS1B,O_WS2S,O_WS2B,
  O_THCS,O_THCB,O_PHCS,O_PHCB,O_GGCS,O_GGCB,O_GXCS,O_GXCB,O_WC1S,O_WC1B,O_WC2S,O_WC2B};

struct ConvArgs { const void* p[36]; int cum[37]; int dst[36]; };

typedef __attribute__((ext_vector_type(8))) short short8;   // 8 bf16 (4 VGPRs)
typedef __attribute__((ext_vector_type(4))) float fragf4;   // MFMA C/D

union FragU { unsigned int w[4]; short8 s8; };

__device__ __forceinline__ float sigf(float v){ return 1.0f/(1.0f+expf(-v)); }
__device__ __forceinline__ float hb2f(unsigned short h){ return __uint_as_float(((unsigned)h)<<16); }
__device__ __forceinline__ unsigned short f2hb(float v){
  __hip_bfloat16 hb = __float2bfloat16(v);
  return *reinterpret_cast<unsigned short*>(&hb);
}
__device__ __forceinline__ float loadx(const void* x, int flag, size_t idx){
  if (flag) return hb2f(((const unsigned short*)x)[idx]);
  return ((const float*)x)[idx];
}

// ---- kd: dtype probe. bf16 data -> ~all sane exponents; f32-misread -> ~62%.
__global__ void kd_detect(const void* x, int* flag){
  __shared__ int cnt[256];
  int t = threadIdx.x;
  const unsigned short* h = (const unsigned short*)x;
  int c = 0;
  for (int k=0;k<4;k++){
    unsigned short v = h[t*4+k];
    int e = (v>>7)&0xFF;
    c += (e==0 || (e>=97 && e<=157)) ? 1 : 0;
  }
  cnt[t] = c;
  __syncthreads();
  for (int s=128; s; s>>=1){ if (t<s) cnt[t]+=cnt[t+s]; __syncthreads(); }
  if (t==0) *flag = (cnt[0] >= 973) ? 1 : 0;
}

// ---- kc: convert all non-x inputs to f32 arena wf
__global__ void kc_convert(ConvArgs a, const int* flagp, float* wf){
  int flag = *flagp;
  int g = blockIdx.x*256 + threadIdx.x;
  if (g >= a.cum[36]) return;
  int i = 0;
  while (g >= a.cum[i+1]) i++;
  int local = g - a.cum[i];
  float v;
  if (flag) v = hb2f(((const unsigned short*)a.p[i])[local]);
  else      v = ((const float*)a.p[i])[local];
  wf[a.dst[i] + local] = v;
}

// ---- kw: bf16 copies of thc/phc/gxc weights + ggs_w halves + wthph[96][128]
#define KW_TOT (5*IS*HW + 96*CC)
__global__ void kw_wbf(const float* wf, unsigned short* wbf){
  int i = blockIdx.x*256 + threadIdx.x;
  if (i >= KW_TOT) return;
  float v;
  if (i < 3*IS*HW){
    int which = i/(IS*HW), r = i - which*(IS*HW);
    int off = which==0?O_THCW:(which==1?O_PHCW:O_GXCW);
    v = wf[off + r];
  } else if (i < 5*IS*HW){
    int which = i/(IS*HW), r = i - which*(IS*HW);
    int row = r/HW, col = r - row*HW;
    v = wf[O_GGSW + row*(2*HW) + (which-3)*HW + col];
  } else {
    int r = i - 5*IS*HW;               // 0..12287
    int row = r >> 7, col = r & 127;   // th 0-31, ph 32-63 (contig at wf+0), gxs 64-95
    v = (row < 64) ? wf[row*CC + col] : wf[O_GXSW + (row-64)*CC + col];
  }
  wbf[i] = f2hb(v);
}

// ---- k0: ws1bf [64][224] bf16 (zero-padded W1aug: col0 = gx weight)
__global__ void k0_ws1bf(const float* wf, unsigned int* ws1bf32){
  int i = blockIdx.x*256 + threadIdx.x;      // 64*112 u32
  if (i >= 64*112) return;
  int o2 = i/112, k2 = i - o2*112;
  int k = k2*2;
  float v0 = (o2<DS && k<197)   ? wf[O_WS1W + o2*197 + k]   : 0.f;
  float v1 = (o2<DS && k+1<197) ? wf[O_WS1W + o2*197 + k+1] : 0.f;
  ws1bf32[i] = (unsigned)f2hb(v0) | ((unsigned)f2hb(v1)<<16);
}

// ---- k1k2 v3 (R13, MFMA): theta/phi/g_xs projections.
#define XST 68   // Xl u32 stride per p-row (272B: 16B-aligned b128 reads)
__global__ __launch_bounds__(256) void k1k2_mfma(const void* x, const int* flagp,
    const float* wf, const unsigned short* wthph, unsigned short* thph, float* g_xs)
{
  __shared__ __align__(16) unsigned int Xl[64*XST];   // 17.4 KB
  int flag = *flagp;
  int t = threadIdx.x;
  int pt = blockIdx.x % 13, b = blockIdx.x / 13;
  int p0 = pt*64;

  // stage x^T tile: Xl[p][c] bf16 via 2x2 transpose micro-tiles (8 units/thread)
  #pragma unroll
  for (int k=0; k<8; k++){
    int idx = k*256 + t;
    int q = idx & 31;              // p-pair (coalesced across lanes)
    int c2 = idx >> 5;             // c-pair, 0..63
    int p = p0 + 2*q, c = 2*c2;
    unsigned int w0 = 0u, w1 = 0u;
    if (p < HW){                   // HW even, p even -> p+1 < HW too
      if (flag){
        const unsigned short* xb = (const unsigned short*)x + (size_t)b*CC*HW;
        unsigned int a0 = *(const unsigned int*)(xb + (size_t)c*HW + p);
        unsigned int a1 = *(const unsigned int*)(xb + (size_t)(c+1)*HW + p);
        w0 = (a0 & 0xffffu) | (a1 << 16);
        w1 = (a0 >> 16) | (a1 & 0xffff0000u);
      } else {
        const float* xb = (const float*)x + (size_t)b*CC*HW;
        float2 a0 = *(const float2*)(xb + (size_t)c*HW + p);
        float2 a1 = *(const float2*)(xb + (size_t)(c+1)*HW + p);
        w0 = (unsigned)f2hb(a0.x) | ((unsigned)f2hb(a1.x)<<16);
        w1 = (unsigned)f2hb(a0.y) | ((unsigned)f2hb(a1.y)<<16);
      }
    }
    Xl[(2*q+0)*XST + c2] = w0;
    Xl[(2*q+1)*XST + c2] = w1;
  }
  __syncthreads();

  int lane = t & 63, w = t >> 6;
  int m16 = lane & 15, kq = lane >> 4;
  fragf4 acc[6];
  #pragma unroll
  for (int mt=0; mt<6; mt++)
    #pragma unroll
    for (int r=0;r<4;r++) acc[mt][r] = 0.f;

  const unsigned short* Xu = (const unsigned short*)Xl;
  #pragma unroll
  for (int kk=0; kk<4; kk++){
    short8 bfr = *(const short8*)(Xu + (w*16+m16)*(2*XST) + kk*32 + kq*8);
    #pragma unroll
    for (int mt=0; mt<6; mt++){
      short8 af = *(const short8*)(wthph + (mt*16+m16)*CC + kk*32 + kq*8);
      acc[mt] = __builtin_amdgcn_mfma_f32_16x16x32_bf16(af, bfr, acc[mt], 0,0,0);
    }
  }

  int p = p0 + w*16 + m16;
  // theta/phi epilogue: o = mt*16 + kq*4 + r in [0,64)
  #pragma unroll
  for (int mt=0; mt<4; mt++){
    #pragma unroll
    for (int r=0;r<4;r++){
      int o = mt*16 + kq*4 + r;
      float sc = (o<32) ? wf[O_THS+o] : wf[O_PHS+o-32];
      float sh = (o<32) ? wf[O_THB+o] : wf[O_PHB+o-32];
      float v = fmaxf(sc*acc[mt][r] + sh, 0.f);
      if (p < HW) thph[((size_t)b*64 + o)*HW + p] = f2hb(v);
    }
  }
  // gxs epilogue: relu'd rows 64..95, mean over o via kq-lane reduce
  float gs = 0.f;
  #pragma unroll
  for (int mt=4; mt<6; mt++){
    #pragma unroll
    for (int r=0;r<4;r++){
      int o = (mt-4)*16 + kq*4 + r;
      gs += fmaxf(wf[O_GXSS+o]*acc[mt][r] + wf[O_GXSB+o], 0.f);
    }
  }
  gs += __shfl_xor(gs, 16);
  gs += __shfl_xor(gs, 32);
  if (kq == 0 && p < HW) g_xs[(size_t)b*HW + p] = gs*(1.f/32.f);
}

// ---- k3 v4 (R14, MFMA): writes acomb[b][208][64] bf16 in k4's Al row layout:
//      row o = [Aphi[o][c=0..31] | Atheta[o][c=0..31]]. which=0 -> cols 0-31,
//      which=1 -> cols 32-63. Values identical to old f32 path + f2hb.
#define K3ST 40
__global__ __launch_bounds__(256) void k3_mfma(const unsigned short* wggs,
    const unsigned short* thph, unsigned short* acomb)
{
  __shared__ __align__(16) unsigned short Al[112*K3ST];
  __shared__ __align__(16) unsigned short Bl[32*K3ST];
  int t = threadIdx.x;
  int mh = blockIdx.x & 1;
  int b  = (blockIdx.x >> 1) & 63;
  int which = blockIdx.x >> 7;
  int m0 = mh*112;
  const unsigned short* wsrc = wggs + (size_t)which*IS*HW;
  const unsigned short* ssrc = thph + ((size_t)b*64 + (which ? 0 : 32))*HW;
  int lane = t & 63, w = t >> 6;
  int m16 = lane & 15, kq = lane >> 4;
  fragf4 acc[2][2];
  #pragma unroll
  for (int i=0;i<2;i++)
    #pragma unroll
    for (int nt=0;nt<2;nt++)
      #pragma unroll
      for (int r=0;r<4;r++) acc[i][nt][r] = 0.f;

  for (int kk=0; kk<25; kk++){
    int p0 = kk*32;
    __syncthreads();
    for (int i=t; i<112*4; i+=256){
      int row = i>>2, q = i&3;
      uint4 v = make_uint4(0u,0u,0u,0u);
      int gr = m0 + row, p = p0 + q*8;
      if (gr < IS && p+8 <= HW)
        v = *(const uint4*)(wsrc + (size_t)gr*HW + p);
      *(uint4*)(Al + row*K3ST + q*8) = v;
    }
    if (t < 128){
      int row = t>>2, q = t&3;
      uint4 v = make_uint4(0u,0u,0u,0u);
      int p = p0 + q*8;
      if (p+8 <= HW)
        v = *(const uint4*)(ssrc + (size_t)row*HW + p);
      *(uint4*)(Bl + row*K3ST + q*8) = v;
    }
    __syncthreads();
    short8 bfr[2];
    #pragma unroll
    for (int nt=0;nt<2;nt++)
      bfr[nt] = *(const short8*)(Bl + (nt*16+m16)*K3ST + kq*8);
    #pragma unroll
    for (int i=0;i<2;i++){
      int mt = w + 4*i;
      if (mt < 7){
        short8 af = *(const short8*)(Al + (mt*16+m16)*K3ST + kq*8);
        acc[i][0] = __builtin_amdgcn_mfma_f32_16x16x32_bf16(af, bfr[0], acc[i][0], 0,0,0);
        acc[i][1] = __builtin_amdgcn_mfma_f32_16x16x32_bf16(af, bfr[1], acc[i][1], 0,0,0);
      }
    }
  }
  unsigned short* dst = acomb + (size_t)b*208*64 + which*32;
  #pragma unroll
  for (int i=0;i<2;i++){
    int mt = w + 4*i;
    if (mt >= 7) continue;
    #pragma unroll
    for (int r=0;r<4;r++){
      int o = m0 + mt*16 + kq*4 + r;
      if (o >= IS) continue;
      #pragma unroll
      for (int nt=0;nt<2;nt++){
        int c = nt*16 + m16;
        dst[(size_t)o*64 + c] = f2hb(acc[i][nt][r]);
      }
    }
  }
}

// ---- k4 v8 (R14, MFMA): fused spatial chain per (b, 64-p tile).
// Al staged as uint4 copies from acomb (pre-packed bf16); stride 72 u16
// (144B, 16B-aligned b128, 2-way banks = free). Sl staged via paired u32.
#define A4ST 72   // Al16 u16 stride
#define ALS 33    // Sl u32 stride
#define GTS 113   // Gt u32 stride (226 u16)
union K4Sh {
  struct { unsigned short Al16[208*A4ST]; unsigned int Sl[64*ALS]; } s1;
  unsigned int Gt[64*GTS];
};
__global__ __launch_bounds__(256,3) void k4_mfma(const void* x, const int* flagp,
    const float* wf, const unsigned short* thph,
    const unsigned short* acomb, const float* g_xs,
    const unsigned int* ws1bf32, unsigned short* x1tp)
{
  __shared__ K4Sh sh;
  __shared__ float ash[64];
  int flag = *flagp;
  int t = threadIdx.x;
  int pt = blockIdx.x % 13, b = blockIdx.x / 13;
  int p0 = pt*64;
  int lane = t & 63, w = t >> 6;
  int col = lane & 15, kq = lane >> 4;

  // Al: 1664 uint4 copies (rows >= IS zeroed)
  const unsigned short* Ab16 = acomb + (size_t)b*208*64;
  for (int i=t; i<208*8; i+=256){
    int row = i>>3, q = i&7;
    uint4 v = make_uint4(0u,0u,0u,0u);
    if (row < IS) v = *(const uint4*)(Ab16 + (size_t)row*64 + q*8);
    *(uint4*)(sh.s1.Al16 + (size_t)row*A4ST + q*8) = v;
  }
  // Sl[p][c-pair]: paired u32 loads from thph (2 p's per unit)
  const unsigned short* tb = thph + (size_t)b*64*HW;
  for (int i=t; i<32*32; i+=256){
    int c2 = i>>5, q = i&31;
    int p = p0 + 2*q;
    unsigned int w0 = 0u, w1 = 0u;
    if (p < HW){                    // p even, HW even -> p+1 < HW
      int c = 2*c2;
      unsigned int a0 = *(const unsigned int*)(tb + (size_t)c*HW + p);
      unsigned int a1 = *(const unsigned int*)(tb + (size_t)(c+1)*HW + p);
      w0 = (a0 & 0xffffu) | (a1 << 16);
      w1 = (a0 >> 16) | (a1 & 0xffff0000u);
    }
    sh.s1.Sl[(2*q+0)*ALS + c2] = w0;
    sh.s1.Sl[(2*q+1)*ALS + c2] = w1;
  }
  __syncthreads();

  fragf4 acc1[13];
  #pragma unroll
  for (int nt=0; nt<13; nt++)
    #pragma unroll
    for (int r=0;r<4;r++) acc1[nt][r] = 0.f;
  #pragma unroll
  for (int kk=0; kk<2; kk++){
    FragU af;
    #pragma unroll
    for (int q=0;q<4;q++) af.w[q] = sh.s1.Sl[(w*16+col)*ALS + kk*16 + kq*4 + q];
    #pragma unroll
    for (int nt=0; nt<13; nt++){
      short8 bf8 = *(const short8*)(sh.s1.Al16 + (size_t)(nt*16+col)*A4ST + kk*32 + kq*8);
      acc1[nt] = __builtin_amdgcn_mfma_f32_16x16x32_bf16(af.s8, bf8, acc1[nt], 0,0,0);
    }
  }
  __syncthreads();   // Al/Sl dead; Gt aliases them

  unsigned short* Gt16 = (unsigned short*)sh.Gt;
  for (int i=t; i<64*9; i+=256){
    int pp = i/9, q = i - pp*9;
    sh.Gt[pp*GTS + 104 + q] = 0u;
  }
  if (t < 64){
    int p = p0 + t;
    float gx = (p < HW) ? g_xs[b*HW + p] : 0.f;
    Gt16[t*226 + 0] = f2hb(gx);
  }
  #pragma unroll
  for (int nt=0; nt<13; nt++){
    int o = nt*16 + col;
    float sc = wf[O_GGSS + o], shf = wf[O_GGSB + o];
    #pragma unroll
    for (int r=0;r<4;r++){
      int pp = w*16 + kq*4 + r;
      float g = fmaxf(sc*acc1[nt][r] + shf, 0.f);
      Gt16[pp*226 + 1 + o] = f2hb(g);
    }
  }
  __syncthreads();

  fragf4 acc2[4];
  #pragma unroll
  for (int nt=0; nt<4; nt++)
    #pragma unroll
    for (int r=0;r<4;r++) acc2[nt][r] = 0.f;
  #pragma unroll
  for (int kk=0; kk<7; kk++){
    FragU af;
    #pragma unroll
    for (int q=0;q<4;q++) af.w[q] = sh.Gt[(w*16+col)*GTS + kk*16 + kq*4 + q];
    #pragma unroll
    for (int nt=0; nt<4; nt++){
      FragU bf;
      #pragma unroll
      for (int q=0;q<4;q++) bf.w[q] = ws1bf32[(nt*16+col)*112 + kk*16 + kq*4 + q];
      acc2[nt] = __builtin_amdgcn_mfma_f32_16x16x32_bf16(af.s8, bf.s8, acc2[nt], 0,0,0);
    }
  }

  float wys[4] = {0.f,0.f,0.f,0.f};
  #pragma unroll
  for (int nt=0; nt<4; nt++){
    int o2 = nt*16 + col;
    bool vd = (o2 < DS);
    float s1 = vd ? wf[O_WS1S+o2] : 0.f;
    float b1 = vd ? wf[O_WS1B+o2] : 0.f;
    float w2 = vd ? wf[O_WS2W+o2] : 0.f;
    #pragma unroll
    for (int r=0;r<4;r++){
      float z = fmaxf(s1*acc2[nt][r] + b1, 0.f);
      wys[r] += w2*z;
    }
  }
  #pragma unroll
  for (int m=1; m<16; m<<=1){
    #pragma unroll
    for (int r=0;r<4;r++) wys[r] += __shfl_xor(wys[r], m, 16);
  }
  if (col == 0){
    float s2 = wf[O_WS2S], b2 = wf[O_WS2B];
    #pragma unroll
    for (int r=0;r<4;r++){
      int pp = w*16 + kq*4 + r;
      ash[pp] = sigf(s2*wys[r] + b2);
    }
  }
  __syncthreads();

  // x1 epilogue, 4-wide (p = p0 + q*4; p<HW <=> p+4<=HW since p%4==0, HW%4==0)
  for (int i=t; i<CC*16; i+=256){
    int c = i>>4, q = i&15;
    int p = p0 + q*4;
    if (p < HW){
      float a0 = ash[q*4+0], a1 = ash[q*4+1], a2 = ash[q*4+2], a3 = ash[q*4+3];
      size_t base = (size_t)b*CC*HW + (size_t)c*HW + p;
      float v0,v1,v2,v3;
      if (flag){
        uint2 u = *(const uint2*)((const unsigned short*)x + base);
        v0 = a0*hb2f((unsigned short)(u.x & 0xffff));
        v1 = a1*hb2f((unsigned short)(u.x >> 16));
        v2 = a2*hb2f((unsigned short)(u.y & 0xffff));
        v3 = a3*hb2f((unsigned short)(u.y >> 16));
      } else {
        float4 xv = *(const float4*)((const float*)x + base);
        v0 = a0*xv.x; v1 = a1*xv.y; v2 = a2*xv.z; v3 = a3*xv.w;
      }
      uint2 o2;
      o2.x = (unsigned)f2hb(v0) | ((unsigned)f2hb(v1)<<16);
      o2.y = (unsigned)f2hb(v2) | ((unsigned)f2hb(v3)<<16);
      *(uint2*)(x1tp + base) = o2;
    }
  }
}

// ---- k8 v3 (R11, MFMA): out[g,c] = relu(sc*(sum_p Wall[g,p]*x1[b,p,c])+sh)
#define KST 40
__global__ __launch_bounds__(256) void k8_mfma(const unsigned short* wbf,
    const unsigned short* x1tp, const float* wf, float* outp)
{
  __shared__ __align__(16) unsigned short Al[48*KST];
  __shared__ __align__(16) unsigned short Bl[128*KST];
  int t = threadIdx.x;
  int j = blockIdx.x & 63;
  int b = (j&7)*8 + (j>>3);
  int mt = blockIdx.x >> 6;          // 0..12
  int m0 = mt*48;
  const unsigned short* xsrc = x1tp + (size_t)b*CC*HW;
  int lane = t & 63, w = t >> 6;
  int m16 = lane & 15, kq = lane >> 4;
  fragf4 acc[3][2];
  #pragma unroll
  for (int st=0; st<3; st++)
    #pragma unroll
    for (int ct=0; ct<2; ct++)
      #pragma unroll
      for (int r=0; r<4; r++) acc[st][ct][r] = 0.f;

  for (int kk=0; kk<25; kk++){
    int p0 = kk*32;
    __syncthreads();
    if (t < 192){
      int row = t>>2, q = t&3;
      uint4 v = make_uint4(0u,0u,0u,0u);
      int g = m0 + row, p = p0 + q*8;
      if (g < 3*IS && p+8 <= HW)
        v = *(const uint4*)(wbf + (size_t)g*HW + p);
      *(uint4*)(Al + row*KST + q*8) = v;
    }
    for (int i=t; i<128*4; i+=256){
      int row = i>>2, q = i&3;
      uint4 v = make_uint4(0u,0u,0u,0u);
      int p = p0 + q*8;
      if (p+8 <= HW)
        v = *(const uint4*)(xsrc + (size_t)row*HW + p);
      *(uint4*)(Bl + row*KST + q*8) = v;
    }
    __syncthreads();
    short8 bfr[2];
    #pragma unroll
    for (int ct=0; ct<2; ct++){
      int n = (w*2+ct)*16 + m16;
      bfr[ct] = *(const short8*)(Bl + n*KST + kq*8);
    }
    #pragma unroll
    for (int st=0; st<3; st++){
      short8 af = *(const short8*)(Al + (st*16+m16)*KST + kq*8);
      acc[st][0] = __builtin_amdgcn_mfma_f32_16x16x32_bf16(af, bfr[0], acc[st][0], 0,0,0);
      acc[st][1] = __builtin_amdgcn_mfma_f32_16x16x32_bf16(af, bfr[1], acc[st][1], 0,0,0);
    }
  }
  #pragma unroll
  for (int st=0; st<3; st++){
    #pragma unroll
    for (int r=0; r<4; r++){
      int g = m0 + st*16 + kq*4 + r;
      if (g >= 3*IS) continue;
      int which = (g >= 2*IS) ? 2 : (g >= IS ? 1 : 0);
      int s = g - which*IS;
      int so = (which==2) ? O_GXCS : O_THCS + which*392;
      float sc = wf[so + s], sh = wf[so + 196 + s];
      float* dst = outp + (size_t)which*(64*IS*CC) + ((size_t)b*IS + s)*CC;
      #pragma unroll
      for (int ct=0; ct<2; ct++){
        int c = (w*2+ct)*16 + m16;
        dst[c] = fmaxf(sc*acc[st][ct][r] + sh, 0.f);
      }
    }
  }
}

// ---- k9 v2 (R12): Bph[b,s,o]=sum_j ggc_w[o,j]*phc[b,s,j]; Bth with thc.
__global__ __launch_bounds__(256) void k9_bfact(const float* wf, const float* thcp,
    const float* phcp, float* Bph, float* Bth)
{
  __shared__ __align__(16) float wtl[32*32*4];   // 16 KB
  int t = threadIdx.x;
  int sq = blockIdx.x & 3;
  int b  = (blockIdx.x >> 2) & 63;
  int which = blockIdx.x >> 8;
  for (int i = t; i < 32*32; i += 256){
    int jc = i >> 5, o = i & 31;
    *(float4*)(wtl + i*4) =
        *(const float4*)(wf + O_GGCW + o*256 + which*CC + jc*4);
  }
  __syncthreads();
  const float* src = which ? thcp : phcp;
  float* dst = which ? Bth : Bph;
  int o = t & 31, sloc = t >> 5;
  int s0 = sq*49;
  float acc[7];
  #pragma unroll
  for (int k=0;k<7;k++) acc[k]=0.f;
  const float* srow[7];
  #pragma unroll
  for (int k=0;k<7;k++){
    int sl = sloc + 8*k;
    srow[k] = src + ((size_t)b*IS + s0 + (sl<49 ? sl : 0))*CC;
  }
  for (int jc=0; jc<32; jc++){
    float4 wv = *(const float4*)(wtl + (jc*32+o)*4);
    #pragma unroll
    for (int k=0;k<7;k++){
      if (sloc + 8*k < 49){
        float4 sv = *(const float4*)(srow[k] + jc*4);
        acc[k] += wv.x*sv.x + wv.y*sv.y + wv.z*sv.z + wv.w*sv.w;
      }
    }
  }
  #pragma unroll
  for (int k=0;k<7;k++){
    int sl = sloc + 8*k;
    if (sl < 49){
      dst[((size_t)b*IS + s0 + sl)*IC + o] = acc[k];
    }
  }
}

// ---- k10a: s-chunk partial accumulation. Grid (b x 14 chunks), thread (d, o-half).
__global__ __launch_bounds__(256) void k10a_part(const float* thcp, const float* phcp,
    const float* gxcp, const float* Bph, const float* Bth,
    float* part, float* gxp)
{
  int t = threadIdx.x;
  int d = t & 127, oh = t >> 7;
  int sc = blockIdx.x % 14, b = blockIdx.x / 14;
  int s0 = sc*14;
  float acc[16];
  #pragma unroll
  for (int o=0;o<16;o++) acc[o]=0.f;
  float gxa = 0.f;
  for (int i=0;i<14;i++){
    int s = s0 + i;
    size_t base = ((size_t)b*IS + s)*CC + d;
    float tv = thcp[base], pv = phcp[base];
    if (oh == 0) gxa += gxcp[base];
    const float* bp = Bph + ((size_t)b*IS + s)*IC + oh*16;
    const float* bt = Bth + ((size_t)b*IS + s)*IC + oh*16;
    #pragma unroll
    for (int o=0;o<16;o++) acc[o] += bp[o]*tv + bt[o]*pv;
  }
  float* pb = part + (((size_t)b*14 + sc)*IC + oh*16)*CC + d;
  #pragma unroll
  for (int o=0;o<16;o++) pb[(size_t)o*CC] = acc[o];
  if (oh == 0) gxp[((size_t)b*14 + sc)*CC + d] = gxa;
}

// ---- k10b: reduce 14 chunks + wc1/wc2/sigmoid epilogue -> c_att[b,d]
__global__ void k10b_catt(const float* wf, const float* part, const float* gxp,
                          float* c_att)
{
  int idx = blockIdx.x*256 + threadIdx.x;    // 64*128 exact
  int d = idx & 127;
  int b = idx >> 7;
  float acc[IC];
  #pragma unroll
  for (int o=0;o<IC;o++) acc[o]=0.f;
  float gx = 0.f;
  for (int sc=0; sc<14; sc++){
    gx += gxp[((size_t)b*14 + sc)*CC + d];
    const float* pb = part + ((size_t)b*14 + sc)*IC*CC + d;
    #pragma unroll
    for (int o=0;o<IC;o++) acc[o] += pb[(size_t)o*CC];
  }
  gx *= (1.f/196.f);
  #pragma unroll
  for (int o=0;o<IC;o++) acc[o] = fmaxf(wf[O_GGCS+o]*acc[o]+wf[O_GGCB+o], 0.f);
  float acc2 = 0.f;
  #pragma unroll
  for (int o2=0;o2<8;o2++){
    float tt = wf[O_WC1W + o2*33]*gx;
    #pragma unroll
    for (int o=0;o<IC;o++) tt += wf[O_WC1W + o2*33+1+o]*acc[o];
    float z = fmaxf(wf[O_WC1S+o2]*tt + wf[O_WC1B+o2], 0.f);
    acc2 += wf[O_WC2W+o2]*z;
  }
  c_att[idx] = sigf(wf[O_WC2S]*acc2 + wf[O_WC2B]);
}

// ---- k12 v2: out[b,c,p] = c_att[b,c]*x1tp[b,c,p] — pure streaming
__global__ void k12_final(const int* flagp, const unsigned int* x1tp2,
                          const float* c_att, void* out)
{
  int i = blockIdx.x*256 + threadIdx.x;      // over BB*CC*HW/2 uints, exact
  int flag = *flagp;
  unsigned int v = x1tp2[i];
  float a = c_att[i/392];                    // 392 uints per (b,c) row
  float v0 = a*hb2f((unsigned short)(v & 0xffff));
  float v1 = a*hb2f((unsigned short)(v >> 16));
  if (flag){
    ((unsigned int*)out)[i] = (unsigned)f2hb(v0) | ((unsigned)f2hb(v1)<<16);
  } else {
    ((float*)out)[2*i+0] = v0;
    ((float*)out)[2*i+1] = v1;
  }
}

extern "C" void kernel_launch(void* const* d_in, const int* in_sizes, int n_in,
                              void* d_out, int out_size, void* d_ws, size_t ws_size,
                              hipStream_t stream)
{
  const void* x = d_in[0];

  float* W = (float*)d_ws;
  int*   flag  = (int*)W;                    // W[0..63] reserved
  float* wf    = W + 64;                     // 800768
  float* theta = wf + WF_TOTAL;              // 1605632 (scratch; part alias)
  unsigned short* thph = (unsigned short*)(theta + 1605632); // 3211264 u16 (old phi slot)
  float* g_xs  = theta + 2*1605632;          // 50176
  float* Aphi  = g_xs + 50176;               // 401408 (acomb lives here)
  float* Atheta= Aphi + 401408;              // 401408
  unsigned short* acomb = (unsigned short*)Aphi;  // 64*208*64 u16 = 851968 (fits 802816 f32 x2)
  unsigned short* x1tp = (unsigned short*)(Atheta + 401408); // 6422528 u16 = 3211264 f32 slots
  float* thcp  = Atheta + 401408 + 3211264;  // 1605632
  float* phcp  = thcp + 1605632;             // 1605632
  float* gxcp  = phcp + 1605632;             // 1605632 (thcp/phcp/gxcp contiguous!)
  float* Bph   = gxcp + 1605632;             // 401408
  float* Bth   = Bph + 401408;               // 401408
  unsigned int* ws1bf32 = (unsigned int*)(Bth + 401408);  // 7168 u32 (slot 9664)
  float* c_att = (float*)(ws1bf32) + 9664;   // 8192
  unsigned short* wbf = (unsigned short*)(c_att + 8192);  // 780608 u16 (~53.9 MiB total)
  unsigned short* wggs = wbf + 3*IS*HW;      // 2*196*784 u16
  unsigned short* wthph = wbf + 5*IS*HW;     // 96*128 u16 (tail of wbf)
  // k10 partials reuse dead theta..Atheta region (4,064,256 contiguous floats):
  float* part = theta;                       // 64*14*32*128 = 3,670,016
  float* gxp  = theta + 3670016;             // 64*14*128  = 114,688 (fits: 3,784,704 < 4,064,256)

  ConvArgs ca;
  ca.cum[0] = 0;
  for (int i=0;i<36;i++){
    ca.p[i] = d_in[i+1];
    ca.cum[i+1] = ca.cum[i] + SRC_SIZES[i];
    ca.dst[i] = DST_OFF[i];
  }

  kd_detect<<<1, 256, 0, stream>>>(x, flag);
  kc_convert<<<(800716+255)/256, 256, 0, stream>>>(ca, flag, wf);
  kw_wbf<<<(KW_TOT+255)/256, 256, 0, stream>>>(wf, wbf);
  k0_ws1bf<<<(64*112+255)/256, 256, 0, stream>>>(wf, ws1bf32);
  k1k2_mfma<<<64*13, 256, 0, stream>>>(x, flag, wf, wthph, thph, g_xs);
  k3_mfma<<<2*64*2, 256, 0, stream>>>(wggs, thph, acomb);
  k4_mfma<<<64*13, 256, 0, stream>>>(x, flag, wf, thph, acomb,
      g_xs, ws1bf32, x1tp);
  k8_mfma<<<13*64, 256, 0, stream>>>(wbf, x1tp, wf, thcp);
  k9_bfact<<<2*64*4, 256, 0, stream>>>(wf, thcp, phcp, Bph, Bth);
  k10a_part<<<64*14, 256, 0, stream>>>(thcp, phcp, gxcp, Bph, Bth, part, gxp);
  k10b_catt<<<(BB*CC)/256, 256, 0, stream>>>(wf, part, gxp, c_att);
  k12_final<<<(BB*CC*HW/2)/256, 256, 0, stream>>>(flag, (const unsigned int*)x1tp,
      c_att, d_out);
}